// Round 1
// baseline (33236.194 us; speedup 1.0000x reference)
//
#include <hip/hip_runtime.h>
#include <hip/hip_bf16.h>

#define BB 8
#define TT 1024
#define DM 512
#define NH 8
#define DK 64
#define DH 2048
#define NL 8
#define ND 8192

// ---------------- block reduce (256 threads, 2 accumulators) ----------------
__device__ __forceinline__ void block_reduce2(float& a, float& b) {
  #pragma unroll
  for (int off = 32; off > 0; off >>= 1) {
    a += __shfl_down(a, off, 64);
    b += __shfl_down(b, off, 64);
  }
  __shared__ float sa[4], sb[4];
  int w = threadIdx.x >> 6;
  if ((threadIdx.x & 63) == 0) { sa[w] = a; sb[w] = b; }
  __syncthreads();
  if (threadIdx.x == 0) {
    sa[0] = sa[0] + sa[1] + sa[2] + sa[3];
    sb[0] = sb[0] + sb[1] + sb[2] + sb[3];
  }
  __syncthreads();
  a = sa[0]; b = sb[0];
}

// ---------------- embedding + LN ----------------
__global__ __launch_bounds__(256) void embed_ln_kernel(
    const int* __restrict__ x, const float* __restrict__ emb,
    const float* __restrict__ pos, float* __restrict__ h) {
  int bt = blockIdx.x;
  int t = bt & (TT - 1);
  int tid = threadIdx.x;
  int row = x[bt];
  float v0 = emb[(size_t)row * DM + tid]       + pos[(size_t)t * DM + tid];
  float v1 = emb[(size_t)row * DM + tid + 256] + pos[(size_t)t * DM + tid + 256];
  float s = v0 + v1, sq = v0 * v0 + v1 * v1;
  block_reduce2(s, sq);
  float mu  = s * (1.0f / DM);
  float var = sq * (1.0f / DM) - mu * mu;
  float rs  = rsqrtf(var + 1e-5f);
  h[(size_t)bt * DM + tid]       = (v0 - mu) * rs;
  h[(size_t)bt * DM + tid + 256] = (v1 - mu) * rs;
}

// ---------------- h = LN(h + sum_i add[bt*rowStride + i*512 + d]) ----------------
__global__ __launch_bounds__(256) void ln_residual_kernel(
    float* __restrict__ h, const float* __restrict__ add, int rowStride, int nsum) {
  int bt = blockIdx.x;
  int tid = threadIdx.x;
  size_t base = (size_t)bt * (size_t)rowStride;
  float v0 = h[(size_t)bt * DM + tid];
  float v1 = h[(size_t)bt * DM + tid + 256];
  for (int i = 0; i < nsum; ++i) {
    v0 += add[base + (size_t)i * DM + tid];
    v1 += add[base + (size_t)i * DM + tid + 256];
  }
  float s = v0 + v1, sq = v0 * v0 + v1 * v1;
  block_reduce2(s, sq);
  float mu  = s * (1.0f / DM);
  float var = sq * (1.0f / DM) - mu * mu;
  float rs  = rsqrtf(var + 1e-5f);
  h[(size_t)bt * DM + tid]       = (v0 - mu) * rs;
  h[(size_t)bt * DM + tid + 256] = (v1 - mu) * rs;
}

// ---------------- generic fp32 GEMM ----------------
// C[M][N] = A[M][K] @ B  (+bias, relu).  B element (k,n) at:
//   B[(n>>CBbits)*CS + (n & (CB-1)) + k*R]
// Tile 128x64, 256 threads, 8x4 per thread.
template<bool RELU, bool HASBIAS>
__global__ __launch_bounds__(256) void gemm_f32(
    const float* __restrict__ A, const float* __restrict__ B,
    const float* __restrict__ bias, float* __restrict__ C,
    int M, int N, int K, int R, int CBbits, size_t CS) {
  __shared__ __align__(16) float As[16][132];  // transposed A tile, padded
  __shared__ __align__(16) float Bs[16][64];
  int tid = threadIdx.x;
  int m0 = blockIdx.x * 128;
  int n0 = blockIdx.y * 64;
  int tx = tid & 15, ty = tid >> 4;

  float acc[8][4];
  #pragma unroll
  for (int r = 0; r < 8; ++r)
    #pragma unroll
    for (int j = 0; j < 4; ++j) acc[r][j] = 0.f;

  int arow = tid >> 2, aq = tid & 3;
  const float* Ap0 = A + (size_t)(m0 + arow) * K + aq * 4;
  const float* Ap1 = Ap0 + (size_t)64 * K;
  int nb = n0 + (tid & 63);
  size_t colbase = ((size_t)(nb >> CBbits)) * CS + (size_t)(nb & ((1 << CBbits) - 1));
  const float* Bp = B + colbase;
  int bk0 = (tid >> 6) * 4;

  for (int k0 = 0; k0 < K; k0 += 16) {
    float4 a0 = *(const float4*)(Ap0 + k0);
    float4 a1 = *(const float4*)(Ap1 + k0);
    float b0 = Bp[(size_t)(k0 + bk0 + 0) * R];
    float b1 = Bp[(size_t)(k0 + bk0 + 1) * R];
    float b2 = Bp[(size_t)(k0 + bk0 + 2) * R];
    float b3 = Bp[(size_t)(k0 + bk0 + 3) * R];
    __syncthreads();
    As[aq * 4 + 0][arow] = a0.x;
    As[aq * 4 + 1][arow] = a0.y;
    As[aq * 4 + 2][arow] = a0.z;
    As[aq * 4 + 3][arow] = a0.w;
    As[aq * 4 + 0][arow + 64] = a1.x;
    As[aq * 4 + 1][arow + 64] = a1.y;
    As[aq * 4 + 2][arow + 64] = a1.z;
    As[aq * 4 + 3][arow + 64] = a1.w;
    Bs[bk0 + 0][tid & 63] = b0;
    Bs[bk0 + 1][tid & 63] = b1;
    Bs[bk0 + 2][tid & 63] = b2;
    Bs[bk0 + 3][tid & 63] = b3;
    __syncthreads();
    #pragma unroll
    for (int kk = 0; kk < 16; ++kk) {
      float a8[8];
      *(float4*)&a8[0] = *(const float4*)&As[kk][ty * 8];
      *(float4*)&a8[4] = *(const float4*)&As[kk][ty * 8 + 4];
      float b4[4];
      *(float4*)&b4[0] = *(const float4*)&Bs[kk][tx * 4];
      #pragma unroll
      for (int r = 0; r < 8; ++r)
        #pragma unroll
        for (int j = 0; j < 4; ++j)
          acc[r][j] = fmaf(a8[r], b4[j], acc[r][j]);
    }
  }
  float4 bv = make_float4(0.f, 0.f, 0.f, 0.f);
  if (HASBIAS) bv = *(const float4*)&bias[n0 + tx * 4];
  #pragma unroll
  for (int r = 0; r < 8; ++r) {
    float4 ov;
    ov.x = acc[r][0] + bv.x;
    ov.y = acc[r][1] + bv.y;
    ov.z = acc[r][2] + bv.z;
    ov.w = acc[r][3] + bv.w;
    if (RELU) {
      ov.x = fmaxf(ov.x, 0.f); ov.y = fmaxf(ov.y, 0.f);
      ov.z = fmaxf(ov.z, 0.f); ov.w = fmaxf(ov.w, 0.f);
    }
    *(float4*)&C[(size_t)(m0 + ty * 8 + r) * N + n0 + tx * 4] = ov;
  }
}

// ---------------- flash-style attention (no max subtraction needed) ----------------
// q,k: [bt][h*64+dk]; v,o: [bt][h*512+dv]. Per block: (b,h, 32-row q-tile).
// P = exp(min(S,50)) masked; out = (P@V) / (rowsum + 1e-10), per head.
#define TQ 32
__global__ __launch_bounds__(256) void attn_kernel(
    const float* __restrict__ q, const float* __restrict__ k,
    const float* __restrict__ v, float* __restrict__ o) {
  __shared__ __align__(16) float Qs[TQ][DK];       // 8 KB
  __shared__ __align__(16) float Ps[TQ][65];       // 8.3 KB (padded)
  __shared__ float rowsumS[TQ];
  __shared__ __align__(16) float KV[16 * 512];     // 32 KB: union Ks[64][65] / Vs[16][512]

  int tid = threadIdx.x;
  int blk = blockIdx.x;
  int tt = blk & 31;           // T/TQ = 32 tiles
  int bh = blk >> 5;
  int b = bh >> 3, hh = bh & 7;

  // load Q tile (32 x 64)
  #pragma unroll
  for (int i = 0; i < 2; ++i) {
    int n = tid + i * 256;
    int r = n >> 4, qd = n & 15;
    float4 val = *(const float4*)&q[(size_t)(b * TT + tt * TQ + r) * 512 + hh * 64 + qd * 4];
    *(float4*)&Qs[r][qd * 4] = val;
  }
  if (tid < TQ) rowsumS[tid] = 0.f;

  float acc[4][16];
  #pragma unroll
  for (int r = 0; r < 4; ++r)
    #pragma unroll
    for (int w = 0; w < 16; ++w) acc[r][w] = 0.f;

  int r0 = (tid >> 5) * 4;          // PV: 4 rows per thread
  int cL = tid & 31;                // PV: cols cL + 32*w
  int srow = tid >> 3, soc = (tid & 7) * 8;   // S: row, 8 cols
  int trow = tt * TQ + srow;

  int nOT = (tt * TQ + TQ - 1) / 64 + 1;
  for (int ot = 0; ot < nOT; ++ot) {
    int o0 = ot * 64;
    __syncthreads();
    // load K tile (64 x 64) into KV as Ks[64][65]
    #pragma unroll
    for (int i = 0; i < 4; ++i) {
      int n = tid + i * 256;
      int r = n >> 4, qd = n & 15;
      float4 val = *(const float4*)&k[(size_t)(b * TT + o0 + r) * 512 + hh * 64 + qd * 4];
      KV[r * 65 + qd * 4 + 0] = val.x;
      KV[r * 65 + qd * 4 + 1] = val.y;
      KV[r * 65 + qd * 4 + 2] = val.z;
      KV[r * 65 + qd * 4 + 3] = val.w;
    }
    __syncthreads();
    // S = Q K^T, P = exp(min(S,50)) masked
    float sacc[8];
    #pragma unroll
    for (int j = 0; j < 8; ++j) sacc[j] = 0.f;
    for (int kkk = 0; kkk < 64; ++kkk) {
      float qv = Qs[srow][kkk];
      #pragma unroll
      for (int j = 0; j < 8; ++j)
        sacc[j] = fmaf(qv, KV[(soc + j) * 65 + kkk], sacc[j]);
    }
    float psum = 0.f;
    #pragma unroll
    for (int j = 0; j < 8; ++j) {
      int oo = o0 + soc + j;
      float p = 0.f;
      if (oo <= trow) p = __expf(fminf(sacc[j], 50.f));
      psum += p;
      Ps[srow][soc + j] = p;
    }
    psum += __shfl_xor(psum, 1, 64);
    psum += __shfl_xor(psum, 2, 64);
    psum += __shfl_xor(psum, 4, 64);
    if ((tid & 7) == 0) rowsumS[srow] += psum;
    // PV in 4 chunks of 16 o-rows (V staged in KV)
    for (int c = 0; c < 4; ++c) {
      __syncthreads();
      #pragma unroll
      for (int i = 0; i < 8; ++i) {
        int n = tid + i * 256;
        int r = n >> 7, qd = n & 127;
        *(float4*)&KV[r * 512 + qd * 4] =
            *(const float4*)&v[(size_t)(b * TT + o0 + c * 16 + r) * (NH * DM) + hh * DM + qd * 4];
      }
      __syncthreads();
      #pragma unroll
      for (int oo = 0; oo < 16; ++oo) {
        float vv[16];
        #pragma unroll
        for (int w = 0; w < 16; ++w) vv[w] = KV[oo * 512 + cL + 32 * w];
        #pragma unroll
        for (int r = 0; r < 4; ++r) {
          float pr = Ps[r0 + r][c * 16 + oo];
          #pragma unroll
          for (int w = 0; w < 16; ++w) acc[r][w] = fmaf(pr, vv[w], acc[r][w]);
        }
      }
    }
  }
  __syncthreads();
  #pragma unroll
  for (int r = 0; r < 4; ++r) {
    float rs = 1.0f / (rowsumS[r0 + r] + 1e-10f);
    #pragma unroll
    for (int w = 0; w < 16; ++w) {
      o[(size_t)(b * TT + tt * TQ + r0 + r) * (NH * DM) + hh * DM + cL + 32 * w] = acc[r][w] * rs;
    }
  }
}

extern "C" void kernel_launch(void* const* d_in, const int* in_sizes, int n_in,
                              void* d_out, int out_size, void* d_ws, size_t ws_size,
                              hipStream_t stream) {
  (void)in_sizes; (void)n_in; (void)out_size; (void)ws_size;
  const int*   x   = (const int*)d_in[0];
  // d_in[1]=last_only (False), d_in[2]=capture_stats (unused)
  const float* emb = (const float*)d_in[3];
  const float* pos = (const float*)d_in[4];
  const float* wq  = (const float*)d_in[5];
  const float* wk  = (const float*)d_in[6];
  const float* wv  = (const float*)d_in[7];
  const float* m0  = (const float*)d_in[8];
  const float* mb  = (const float*)d_in[9];
  const float* m1  = (const float*)d_in[10];
  const float* ue  = (const float*)d_in[11];
  const float* ub  = (const float*)d_in[12];
  float* out = (float*)d_out;
  float* ws  = (float*)d_ws;

  const int M = BB * TT;                 // 8192 rows
  float* h  = ws;                        // 4M floats
  float* qb = ws + 4194304;              // 4M
  float* kb = ws + 8388608;              // 4M
  float* yb = ws + 12582912;             // 4M  (total ws use: 64 MiB)
  float* Vb  = out;                      // 33.5M floats (d_out scratch)
  float* Ob  = out + 33554432;           // 33.5M floats
  float* hid = out;                      // MLP hidden reuses V region

  embed_ln_kernel<<<M, 256, 0, stream>>>(x, emb, pos, h);

  for (int l = 0; l < NL; ++l) {
    const float* wql = wq + (size_t)l * NH * DM * DK;
    const float* wkl = wk + (size_t)l * NH * DM * DK;
    const float* wvl = wv + (size_t)l * NH * DM * DM;
    // q,k: [bt][h*64+dk]  (N=512, B col n=(h,dk): base h*32768 + dk, row stride 64)
    gemm_f32<false, false><<<dim3(64, 8), 256, 0, stream>>>(
        h, wql, nullptr, qb, M, 512, 512, 64, 6, (size_t)DM * DK);
    gemm_f32<false, false><<<dim3(64, 8), 256, 0, stream>>>(
        h, wkl, nullptr, kb, M, 512, 512, 64, 6, (size_t)DM * DK);
    // v: [bt][h*512+dv]  (N=4096, base h*262144 + dv, row stride 512)
    gemm_f32<false, false><<<dim3(64, 64), 256, 0, stream>>>(
        h, wvl, nullptr, Vb, M, 4096, 512, 512, 9, (size_t)DM * DM);
    attn_kernel<<<BB * NH * (TT / TQ), 256, 0, stream>>>(qb, kb, Vb, Ob);
    ln_residual_kernel<<<M, 256, 0, stream>>>(h, Ob, NH * DM, NH);   // h = LN(h + sum_heads O)
    // MLP
    gemm_f32<true, true><<<dim3(64, 32), 256, 0, stream>>>(
        h, m0 + (size_t)l * DM * DH, mb + (size_t)l * DH, hid, M, DH, DM, DH, 11, 0);
    gemm_f32<false, false><<<dim3(64, 8), 256, 0, stream>>>(
        hid, m1 + (size_t)l * DH * DM, nullptr, yb, M, DM, DH, DM, 9, 0);
    ln_residual_kernel<<<M, 256, 0, stream>>>(h, yb, DM, 1);         // h = LN(h + y)
  }
  // logits = h @ unembedding + bias  -> overwrites all of d_out
  gemm_f32<false, true><<<dim3(64, 128), 256, 0, stream>>>(
      h, ue, ub, out, M, ND, DM, ND, 13, 0);
}

// Round 2
// 10720.989 us; speedup vs baseline: 3.1001x; 3.1001x over previous
//
#include <hip/hip_runtime.h>
#include <hip/hip_bf16.h>

#define BB 8
#define TT 1024
#define DM 512
#define NH 8
#define DK 64
#define DH 2048
#define NL 8
#define ND 8192

typedef __attribute__((ext_vector_type(8))) short short8v;
typedef __attribute__((ext_vector_type(4))) float f32x4;
typedef __attribute__((ext_vector_type(4))) unsigned short ushort4v;

#define MFMA16(a, b, c) __builtin_amdgcn_mfma_f32_16x16x32_bf16(a, b, c, 0, 0, 0)

__device__ __forceinline__ unsigned short bf16_bits(float f) {
  __hip_bfloat16 b = __float2bfloat16(f);
  union { __hip_bfloat16 h; unsigned short u; } cv;
  cv.h = b;
  return cv.u;
}
__device__ __forceinline__ float bits_to_f32(unsigned short u) {
  union { __hip_bfloat16 h; unsigned short u; } cv;
  cv.u = u;
  return __bfloat162float(cv.h);
}

// ---------------- block reduce (256 threads, 2 accumulators) ----------------
__device__ __forceinline__ void block_reduce2(float& a, float& b) {
  #pragma unroll
  for (int off = 32; off > 0; off >>= 1) {
    a += __shfl_down(a, off, 64);
    b += __shfl_down(b, off, 64);
  }
  __shared__ float sa[4], sb[4];
  int w = threadIdx.x >> 6;
  if ((threadIdx.x & 63) == 0) { sa[w] = a; sb[w] = b; }
  __syncthreads();
  if (threadIdx.x == 0) {
    sa[0] = sa[0] + sa[1] + sa[2] + sa[3];
    sb[0] = sb[0] + sb[1] + sb[2] + sb[3];
  }
  __syncthreads();
  a = sa[0]; b = sb[0];
}

// ---------------- embedding + LN ----------------
__global__ __launch_bounds__(256) void embed_ln_kernel(
    const int* __restrict__ x, const float* __restrict__ emb,
    const float* __restrict__ pos, float* __restrict__ h) {
  int bt = blockIdx.x;
  int t = bt & (TT - 1);
  int tid = threadIdx.x;
  int row = x[bt];
  float v0 = emb[(size_t)row * DM + tid]       + pos[(size_t)t * DM + tid];
  float v1 = emb[(size_t)row * DM + tid + 256] + pos[(size_t)t * DM + tid + 256];
  float s = v0 + v1, sq = v0 * v0 + v1 * v1;
  block_reduce2(s, sq);
  float mu  = s * (1.0f / DM);
  float var = sq * (1.0f / DM) - mu * mu;
  float rs  = rsqrtf(var + 1e-5f);
  h[(size_t)bt * DM + tid]       = (v0 - mu) * rs;
  h[(size_t)bt * DM + tid + 256] = (v1 - mu) * rs;
}

// ---------------- h = LN(h + sum_i add[bt*rowStride + i*512 + d]) ----------------
__global__ __launch_bounds__(256) void ln_residual_kernel(
    float* __restrict__ h, const float* __restrict__ add, int rowStride, int nsum) {
  int bt = blockIdx.x;
  int tid = threadIdx.x;
  size_t base = (size_t)bt * (size_t)rowStride;
  float v0 = h[(size_t)bt * DM + tid];
  float v1 = h[(size_t)bt * DM + tid + 256];
  for (int i = 0; i < nsum; ++i) {
    v0 += add[base + (size_t)i * DM + tid];
    v1 += add[base + (size_t)i * DM + tid + 256];
  }
  float s = v0 + v1, sq = v0 * v0 + v1 * v1;
  block_reduce2(s, sq);
  float mu  = s * (1.0f / DM);
  float var = sq * (1.0f / DM) - mu * mu;
  float rs  = rsqrtf(var + 1e-5f);
  h[(size_t)bt * DM + tid]       = (v0 - mu) * rs;
  h[(size_t)bt * DM + tid + 256] = (v1 - mu) * rs;
}

// ---------------- generic fp32 GEMM with epilogue modes ----------------
// C = A[M][K] @ B.  B element (k,n) at B[(n>>CBbits)*CS + (n & (CB-1)) + k*R]
// MODE 0: f32 out          MODE 1: f32 bias+relu     MODE 2: f32 bias
// MODE 3: bf16 hi/lo out to O0/O1, layout [b][h][t][dk] (N=512, one head per n-block)
// MODE 4: bf16 transposed out to O0, layout [b][h][dv][t]
template<int MODE>
__global__ __launch_bounds__(256) void gemm_f32(
    const float* __restrict__ A, const float* __restrict__ B,
    const float* __restrict__ bias, float* __restrict__ C,
    __hip_bfloat16* __restrict__ O0, __hip_bfloat16* __restrict__ O1,
    int M, int N, int K, int R, int CBbits, size_t CS) {
  __shared__ __align__(16) float As[16][132];
  __shared__ __align__(16) float Bs[16][64];
  int tid = threadIdx.x;
  int m0 = blockIdx.x * 128;
  int n0 = blockIdx.y * 64;
  int tx = tid & 15, ty = tid >> 4;

  float acc[8][4];
  #pragma unroll
  for (int r = 0; r < 8; ++r)
    #pragma unroll
    for (int j = 0; j < 4; ++j) acc[r][j] = 0.f;

  int arow = tid >> 2, aq = tid & 3;
  const float* Ap0 = A + (size_t)(m0 + arow) * K + aq * 4;
  const float* Ap1 = Ap0 + (size_t)64 * K;
  int nb = n0 + (tid & 63);
  size_t colbase = ((size_t)(nb >> CBbits)) * CS + (size_t)(nb & ((1 << CBbits) - 1));
  const float* Bp = B + colbase;
  int bk0 = (tid >> 6) * 4;

  for (int k0 = 0; k0 < K; k0 += 16) {
    float4 a0 = *(const float4*)(Ap0 + k0);
    float4 a1 = *(const float4*)(Ap1 + k0);
    float b0 = Bp[(size_t)(k0 + bk0 + 0) * R];
    float b1 = Bp[(size_t)(k0 + bk0 + 1) * R];
    float b2 = Bp[(size_t)(k0 + bk0 + 2) * R];
    float b3 = Bp[(size_t)(k0 + bk0 + 3) * R];
    __syncthreads();
    As[aq * 4 + 0][arow] = a0.x;
    As[aq * 4 + 1][arow] = a0.y;
    As[aq * 4 + 2][arow] = a0.z;
    As[aq * 4 + 3][arow] = a0.w;
    As[aq * 4 + 0][arow + 64] = a1.x;
    As[aq * 4 + 1][arow + 64] = a1.y;
    As[aq * 4 + 2][arow + 64] = a1.z;
    As[aq * 4 + 3][arow + 64] = a1.w;
    Bs[bk0 + 0][tid & 63] = b0;
    Bs[bk0 + 1][tid & 63] = b1;
    Bs[bk0 + 2][tid & 63] = b2;
    Bs[bk0 + 3][tid & 63] = b3;
    __syncthreads();
    #pragma unroll
    for (int kk = 0; kk < 16; ++kk) {
      float a8[8];
      *(float4*)&a8[0] = *(const float4*)&As[kk][ty * 8];
      *(float4*)&a8[4] = *(const float4*)&As[kk][ty * 8 + 4];
      float b4[4];
      *(float4*)&b4[0] = *(const float4*)&Bs[kk][tx * 4];
      #pragma unroll
      for (int r = 0; r < 8; ++r)
        #pragma unroll
        for (int j = 0; j < 4; ++j)
          acc[r][j] = fmaf(a8[r], b4[j], acc[r][j]);
    }
  }

  if (MODE == 3) {
    int head = n0 >> 6;       // N=512: one 64-wide n-block per head
    int dk0 = tx * 4;
    #pragma unroll
    for (int r = 0; r < 8; ++r) {
      int m = m0 + ty * 8 + r;
      size_t base = (((size_t)(m >> 10) * NH + head) * TT + (m & (TT - 1))) * DK + dk0;
      ushort4v hi, lo;
      #pragma unroll
      for (int j = 0; j < 4; ++j) {
        float v = acc[r][j];
        unsigned short hb = bf16_bits(v);
        hi[j] = hb;
        lo[j] = bf16_bits(v - bits_to_f32(hb));
      }
      *(ushort4v*)((unsigned short*)O0 + base) = hi;
      *(ushort4v*)((unsigned short*)O1 + base) = lo;
    }
  } else if (MODE == 4) {
    int head = n0 >> 9;       // N=4096: 8 n-blocks per head
    int dv0 = (n0 & (DM - 1)) + tx * 4;
    int b = m0 >> 10;
    int t0 = (m0 & (TT - 1)) + ty * 8;
    #pragma unroll
    for (int j = 0; j < 4; ++j) {
      short8v pack;
      #pragma unroll
      for (int r = 0; r < 8; ++r) pack[r] = (short)bf16_bits(acc[r][j]);
      size_t addr = (((size_t)b * NH + head) * DM + dv0 + j) * TT + t0;
      *(short8v*)((unsigned short*)O0 + addr) = pack;
    }
  } else {
    float4 bv = make_float4(0.f, 0.f, 0.f, 0.f);
    if (MODE == 1 || MODE == 2) bv = *(const float4*)&bias[n0 + tx * 4];
    #pragma unroll
    for (int r = 0; r < 8; ++r) {
      float4 ov;
      ov.x = acc[r][0] + bv.x;
      ov.y = acc[r][1] + bv.y;
      ov.z = acc[r][2] + bv.z;
      ov.w = acc[r][3] + bv.w;
      if (MODE == 1) {
        ov.x = fmaxf(ov.x, 0.f); ov.y = fmaxf(ov.y, 0.f);
        ov.z = fmaxf(ov.z, 0.f); ov.w = fmaxf(ov.w, 0.f);
      }
      *(float4*)&C[(size_t)(m0 + ty * 8 + r) * N + n0 + tx * 4] = ov;
    }
  }
}

// ---------------- MFMA flash attention ----------------
// Per block: (b,h, 64-row q-tile). 4 waves. Wave w: S rows [w*16,w*16+16),
// PV dv-cols [w*128,(w+1)*128). S = Qhi·Khi + Qlo·Khi + Qhi·Klo (hi/lo bf16 split).
// P = exp(min(S,50)) masked, unnormalized sums in f32; divide at the end.
__global__ __launch_bounds__(256, 2) void attn_mfma_kernel(
    const __hip_bfloat16* __restrict__ qh_, const __hip_bfloat16* __restrict__ ql_,
    const __hip_bfloat16* __restrict__ kh_, const __hip_bfloat16* __restrict__ kl_,
    const __hip_bfloat16* __restrict__ vt_, float* __restrict__ o) {
  __shared__ __align__(16) unsigned short Pl[64 * 64];   // swizzled bf16 P
  __shared__ float rs_lds[64];

  const unsigned short* qhp = (const unsigned short*)qh_;
  const unsigned short* qlp = (const unsigned short*)ql_;
  const unsigned short* khp = (const unsigned short*)kh_;
  const unsigned short* klp = (const unsigned short*)kl_;
  const unsigned short* vtp = (const unsigned short*)vt_;

  int tid = threadIdx.x;
  int lane = tid & 63;
  int w = tid >> 6;
  int l15 = lane & 15, g = lane >> 4;
  int blk = blockIdx.x;
  int bh = blk & 63;
  int tt = 15 - (blk >> 6);          // heaviest causal tiles dispatch first

  if (tid < 64) rs_lds[tid] = 0.f;

  // Q fragments (A: row=l15 -> q_local = w*16+l15, k = kstep*32 + g*8 + i)
  size_t qbase = (((size_t)bh * TT) + tt * 64 + w * 16 + l15) * DK + g * 8;
  short8v qfh[2], qfl[2];
  qfh[0] = *(const short8v*)(qhp + qbase);
  qfh[1] = *(const short8v*)(qhp + qbase + 32);
  qfl[0] = *(const short8v*)(qlp + qbase);
  qfl[1] = *(const short8v*)(qlp + qbase + 32);

  f32x4 oacc[4][8];
  #pragma unroll
  for (int qt = 0; qt < 4; ++qt)
    #pragma unroll
    for (int dv = 0; dv < 8; ++dv)
      #pragma unroll
      for (int r = 0; r < 4; ++r) oacc[qt][dv][r] = 0.f;

  __syncthreads();

  for (int ot = 0; ot <= tt; ++ot) {
    int ob = ot * 64;
    bool diag = (ot == tt);
    // K fragments (B: col=l15 -> o_local = ct*16+l15, same k pattern as A)
    size_t kbase = (((size_t)bh * TT) + ob + l15) * DK + g * 8;
    short8v kfh[4][2], kfl[4][2];
    #pragma unroll
    for (int ct = 0; ct < 4; ++ct) {
      size_t kb2 = kbase + (size_t)ct * 16 * DK;
      kfh[ct][0] = *(const short8v*)(khp + kb2);
      kfh[ct][1] = *(const short8v*)(khp + kb2 + 32);
      kfl[ct][0] = *(const short8v*)(klp + kb2);
      kfl[ct][1] = *(const short8v*)(klp + kb2 + 32);
    }
    f32x4 sacc[4];
    #pragma unroll
    for (int ct = 0; ct < 4; ++ct)
      #pragma unroll
      for (int r = 0; r < 4; ++r) sacc[ct][r] = 0.f;
    #pragma unroll
    for (int ct = 0; ct < 4; ++ct) {
      #pragma unroll
      for (int ks = 0; ks < 2; ++ks) {
        sacc[ct] = MFMA16(qfh[ks], kfh[ct][ks], sacc[ct]);
        sacc[ct] = MFMA16(qfl[ks], kfh[ct][ks], sacc[ct]);
        sacc[ct] = MFMA16(qfh[ks], kfl[ct][ks], sacc[ct]);
      }
    }
    // exp + mask + row-sum + P->LDS (bf16, XOR-swizzled)
    float psum[4] = {0.f, 0.f, 0.f, 0.f};
    #pragma unroll
    for (int ct = 0; ct < 4; ++ct) {
      #pragma unroll
      for (int r = 0; r < 4; ++r) {
        float s = sacc[ct][r];
        float p = __expf(fminf(s, 50.f));
        if (diag && (ct * 16 + l15 > w * 16 + g * 4 + r)) p = 0.f;
        psum[r] += p;
        int q = w * 16 + g * 4 + r;
        int byte = (q * 128 + (ct * 16 + l15) * 2) ^ ((q & 7) << 4);
        *(__hip_bfloat16*)((char*)Pl + byte) = __float2bfloat16(p);
      }
    }
    #pragma unroll
    for (int r = 0; r < 4; ++r) {
      float v = psum[r];
      v += __shfl_xor(v, 1, 16);
      v += __shfl_xor(v, 2, 16);
      v += __shfl_xor(v, 4, 16);
      v += __shfl_xor(v, 8, 16);
      if (l15 == 0) rs_lds[w * 16 + g * 4 + r] += v;
    }
    __syncthreads();
    // PV: A = P (row=l15 -> q = qt*16+l15, k=o), B = Vt (col=l15 -> dv, k=o)
    #pragma unroll
    for (int ks = 0; ks < 2; ++ks) {
      short8v pf[4];
      #pragma unroll
      for (int qt = 0; qt < 4; ++qt) {
        int q = qt * 16 + l15;
        int byte = (q * 128 + ks * 64 + g * 16) ^ ((q & 7) << 4);
        pf[qt] = *(short8v*)((char*)Pl + byte);
      }
      size_t vbase = ((size_t)bh * DM + w * 128 + l15) * TT + ob + ks * 32 + g * 8;
      #pragma unroll
      for (int dv = 0; dv < 8; ++dv) {
        short8v vf = *(const short8v*)(vtp + vbase + (size_t)dv * 16 * TT);
        #pragma unroll
        for (int qt = 0; qt < 4; ++qt)
          oacc[qt][dv] = MFMA16(pf[qt], vf, oacc[qt][dv]);
      }
    }
    __syncthreads();
  }
  // epilogue: normalize and write O f32 [bt][h*512+dv]
  int b = bh >> 3, hh = bh & 7;
  #pragma unroll
  for (int qt = 0; qt < 4; ++qt) {
    #pragma unroll
    for (int r = 0; r < 4; ++r) {
      int q = qt * 16 + g * 4 + r;
      float rs = 1.0f / (rs_lds[q] + 1e-10f);
      size_t rowbase = ((size_t)(b * TT + tt * 64 + q)) * (NH * DM) + hh * DM + w * 128 + l15;
      #pragma unroll
      for (int dv = 0; dv < 8; ++dv)
        o[rowbase + dv * 16] = oacc[qt][dv][r] * rs;
    }
  }
}

extern "C" void kernel_launch(void* const* d_in, const int* in_sizes, int n_in,
                              void* d_out, int out_size, void* d_ws, size_t ws_size,
                              hipStream_t stream) {
  (void)in_sizes; (void)n_in; (void)out_size; (void)ws_size;
  const int*   x   = (const int*)d_in[0];
  const float* emb = (const float*)d_in[3];
  const float* pos = (const float*)d_in[4];
  const float* wq  = (const float*)d_in[5];
  const float* wk  = (const float*)d_in[6];
  const float* wv  = (const float*)d_in[7];
  const float* m0  = (const float*)d_in[8];
  const float* mb  = (const float*)d_in[9];
  const float* m1  = (const float*)d_in[10];
  const float* ue  = (const float*)d_in[11];
  const float* ub  = (const float*)d_in[12];
  float* out = (float*)d_out;
  float* ws  = (float*)d_ws;

  const int M = BB * TT;                         // 8192 rows
  const int FM = 4194304;                        // 4M floats
  float* h  = ws;                                // [0, 4M) f32
  __hip_bfloat16* qhb = (__hip_bfloat16*)(ws + FM);            // 4M bf16 = 8MB
  __hip_bfloat16* qlb = (__hip_bfloat16*)(ws + FM + 2097152);
  __hip_bfloat16* khb = (__hip_bfloat16*)(ws + 2 * FM);
  __hip_bfloat16* klb = (__hip_bfloat16*)(ws + 2 * FM + 2097152);
  float* yb = ws + 3 * FM;                       // [12M, 16M) f32
  __hip_bfloat16* vtb = (__hip_bfloat16*)out;    // 33.5M bf16 = 67MB in d_out
  float* Ob  = out + 33554432;                   // 33.5M f32
  float* hid = out;                              // MLP hidden reuses vt region (dead)

  embed_ln_kernel<<<M, 256, 0, stream>>>(x, emb, pos, h);

  for (int l = 0; l < NL; ++l) {
    const float* wql = wq + (size_t)l * NH * DM * DK;
    const float* wkl = wk + (size_t)l * NH * DM * DK;
    const float* wvl = wv + (size_t)l * NH * DM * DM;
    gemm_f32<3><<<dim3(64, 8), 256, 0, stream>>>(
        h, wql, nullptr, nullptr, qhb, qlb, M, 512, 512, 64, 6, (size_t)DM * DK);
    gemm_f32<3><<<dim3(64, 8), 256, 0, stream>>>(
        h, wkl, nullptr, nullptr, khb, klb, M, 512, 512, 64, 6, (size_t)DM * DK);
    gemm_f32<4><<<dim3(64, 64), 256, 0, stream>>>(
        h, wvl, nullptr, nullptr, vtb, nullptr, M, 4096, 512, 512, 9, (size_t)DM * DM);
    attn_mfma_kernel<<<BB * NH * (TT / 64), 256, 0, stream>>>(qhb, qlb, khb, klb, vtb, Ob);
    ln_residual_kernel<<<M, 256, 0, stream>>>(h, Ob, NH * DM, NH);
    gemm_f32<1><<<dim3(64, 32), 256, 0, stream>>>(
        h, m0 + (size_t)l * DM * DH, mb + (size_t)l * DH, hid, nullptr, nullptr,
        M, DH, DM, DH, 11, 0);
    gemm_f32<0><<<dim3(64, 8), 256, 0, stream>>>(
        hid, m1 + (size_t)l * DH * DM, nullptr, yb, nullptr, nullptr,
        M, DM, DH, DM, 9, 0);
    ln_residual_kernel<<<M, 256, 0, stream>>>(h, yb, DM, 1);
  }
  gemm_f32<2><<<dim3(64, 128), 256, 0, stream>>>(
      h, ue, ub, out, nullptr, nullptr, M, ND, DM, ND, 13, 0);
}

// Round 3
// 3327.445 us; speedup vs baseline: 9.9885x; 3.2220x over previous
//
#include <hip/hip_runtime.h>
#include <hip/hip_bf16.h>

#define BB 8
#define TT 1024
#define DM 512
#define NH 8
#define DK 64
#define DH 2048
#define NL 8
#define ND 8192

typedef __attribute__((ext_vector_type(8))) short short8v;
typedef __attribute__((ext_vector_type(4))) float f32x4;
typedef __attribute__((ext_vector_type(4))) unsigned short ushort4v;
typedef unsigned short u16;

#define MFMA16(a, b, c) __builtin_amdgcn_mfma_f32_16x16x32_bf16(a, b, c, 0, 0, 0)

__device__ __forceinline__ u16 bf16_bits(float f) {
  union { __hip_bfloat16 h; u16 u; } cv;
  cv.h = __float2bfloat16(f);
  return cv.u;
}
__device__ __forceinline__ float bits_to_f32(u16 u) {
  union { __hip_bfloat16 h; u16 u; } cv;
  cv.u = u;
  return __bfloat162float(cv.h);
}

__device__ __forceinline__ void gload16(const void* g, void* l) {
  __builtin_amdgcn_global_load_lds(
      (const __attribute__((address_space(1))) unsigned int*)g,
      (__attribute__((address_space(3))) unsigned int*)l, 16, 0, 0);
}

#define WAITVM(N) asm volatile("s_waitcnt vmcnt(" #N ")" ::: "memory")
#define BAR() { __builtin_amdgcn_s_barrier(); asm volatile("" ::: "memory"); }

// ---------------- block reduce (256 threads, 2 accumulators) ----------------
__device__ __forceinline__ void block_reduce2(float& a, float& b) {
  #pragma unroll
  for (int off = 32; off > 0; off >>= 1) {
    a += __shfl_down(a, off, 64);
    b += __shfl_down(b, off, 64);
  }
  __shared__ float sa[4], sb[4];
  int w = threadIdx.x >> 6;
  if ((threadIdx.x & 63) == 0) { sa[w] = a; sb[w] = b; }
  __syncthreads();
  if (threadIdx.x == 0) {
    sa[0] = sa[0] + sa[1] + sa[2] + sa[3];
    sb[0] = sb[0] + sb[1] + sb[2] + sb[3];
  }
  __syncthreads();
  a = sa[0]; b = sb[0];
}

__device__ __forceinline__ void store_hilo(u16* hh, u16* hl, size_t i, float v) {
  u16 hb = bf16_bits(v);
  hh[i] = hb;
  hl[i] = bf16_bits(v - bits_to_f32(hb));
}

// ---------------- embedding + LN ----------------
__global__ __launch_bounds__(256) void embed_ln_kernel(
    const int* __restrict__ x, const float* __restrict__ emb,
    const float* __restrict__ pos, float* __restrict__ h,
    u16* __restrict__ hh, u16* __restrict__ hl) {
  int bt = blockIdx.x;
  int t = bt & (TT - 1);
  int tid = threadIdx.x;
  int row = x[bt];
  float v0 = emb[(size_t)row * DM + tid]       + pos[(size_t)t * DM + tid];
  float v1 = emb[(size_t)row * DM + tid + 256] + pos[(size_t)t * DM + tid + 256];
  float s = v0 + v1, sq = v0 * v0 + v1 * v1;
  block_reduce2(s, sq);
  float mu  = s * (1.0f / DM);
  float var = sq * (1.0f / DM) - mu * mu;
  float rs  = rsqrtf(var + 1e-5f);
  float r0 = (v0 - mu) * rs, r1 = (v1 - mu) * rs;
  h[(size_t)bt * DM + tid] = r0;
  h[(size_t)bt * DM + tid + 256] = r1;
  store_hilo(hh, hl, (size_t)bt * DM + tid, r0);
  store_hilo(hh, hl, (size_t)bt * DM + tid + 256, r1);
}

// ---------------- h = LN(h + sum_i add[...]) ----------------
__global__ __launch_bounds__(256) void ln_residual_kernel(
    float* __restrict__ h, const float* __restrict__ add, int rowStride, int nsum,
    u16* __restrict__ hh, u16* __restrict__ hl) {
  int bt = blockIdx.x;
  int tid = threadIdx.x;
  size_t base = (size_t)bt * (size_t)rowStride;
  float v0 = h[(size_t)bt * DM + tid];
  float v1 = h[(size_t)bt * DM + tid + 256];
  for (int i = 0; i < nsum; ++i) {
    v0 += add[base + (size_t)i * DM + tid];
    v1 += add[base + (size_t)i * DM + tid + 256];
  }
  float s = v0 + v1, sq = v0 * v0 + v1 * v1;
  block_reduce2(s, sq);
  float mu  = s * (1.0f / DM);
  float var = sq * (1.0f / DM) - mu * mu;
  float rs  = rsqrtf(var + 1e-5f);
  float r0 = (v0 - mu) * rs, r1 = (v1 - mu) * rs;
  h[(size_t)bt * DM + tid] = r0;
  h[(size_t)bt * DM + tid + 256] = r1;
  store_hilo(hh, hl, (size_t)bt * DM + tid, r0);
  store_hilo(hh, hl, (size_t)bt * DM + tid + 256, r1);
}

// ---------------- weight transpose + bf16 convert ----------------
// in: fp32 head-blocked [G][K][Nb]; out: bf16 [G*Nb][K]
__device__ __forceinline__ void tconv_body(
    const float* __restrict__ in, u16* __restrict__ oh, u16* __restrict__ ol,
    int K, int Nb, bool hilo, float (*T)[65]) {
  int tid = threadIdx.x;
  int k0 = blockIdx.x * 64, n0 = blockIdx.y * 64;
  int g = n0 / Nb;
  const float* src = in + (size_t)g * K * Nb + (n0 - g * Nb);
  #pragma unroll
  for (int rep = 0; rep < 16; ++rep) {
    int idx = rep * 256 + tid;
    int i = idx >> 6, j = idx & 63;
    T[i][j] = src[(size_t)(k0 + i) * Nb + j];
  }
  __syncthreads();
  #pragma unroll
  for (int rep = 0; rep < 16; ++rep) {
    int idx = rep * 256 + tid;
    int j = idx >> 6, i = idx & 63;
    float v = T[i][j];
    size_t oa = (size_t)(n0 + j) * K + k0 + i;
    u16 hb = bf16_bits(v);
    oh[oa] = hb;
    if (hilo) ol[oa] = bf16_bits(v - bits_to_f32(hb));
  }
}

__global__ __launch_bounds__(256) void transpose_layer(
    const float* __restrict__ wq, const float* __restrict__ wk,
    const float* __restrict__ wv, const float* __restrict__ w0,
    const float* __restrict__ w1,
    u16* qh, u16* ql, u16* kh, u16* kl, u16* vT, u16* t0, u16* t1) {
  __shared__ float T[64][65];
  int z = blockIdx.z;
  const float* in;
  u16 *oh, *ol = nullptr;
  int K, Nb, gx, gy;
  bool hilo = false;
  switch (z) {
    case 0: in = wq; oh = qh; ol = ql; K = 512;  Nb = 64;   gx = 8;  gy = 8;  hilo = true; break;
    case 1: in = wk; oh = kh; ol = kl; K = 512;  Nb = 64;   gx = 8;  gy = 8;  hilo = true; break;
    case 2: in = wv; oh = vT;          K = 512;  Nb = 512;  gx = 8;  gy = 64; break;
    case 3: in = w0; oh = t0;          K = 512;  Nb = 2048; gx = 8;  gy = 32; break;
    default: in = w1; oh = t1;         K = 2048; Nb = 512;  gx = 32; gy = 8;  break;
  }
  if ((int)blockIdx.x >= gx || (int)blockIdx.y >= gy) return;
  tconv_body(in, oh, ol, K, Nb, hilo, T);
}

__global__ __launch_bounds__(256) void transpose_ue(
    const float* __restrict__ ue, u16* __restrict__ ueT) {
  __shared__ float T[64][65];
  tconv_body(ue, ueT, nullptr, 512, 8192, false, T);
}

// ---------------- bf16 MFMA GEMM: C[M][N] = A[M][K] @ Bt[N][K]^T ----------------
// 128x128 tile, BK=64, 4 waves (2x2 of 64x64), dbuf LDS + global_load_lds,
// XOR chunk-swizzle (c ^= row&7) on 16B chunks within 128B rows.
// MODE 0: Vt bf16 out [b][h][dv][t]   MODE 1: bf16 bias+relu row-major
// MODE 2: f32 row-major               MODE 3: f32 + bias row-major
template<int MODE>
__global__ __launch_bounds__(256, 2) void gemm_mfma(
    const u16* __restrict__ A, const u16* __restrict__ Bt,
    const float* __restrict__ bias, void* __restrict__ Oo,
    int M, int N, int K) {
  __shared__ u16 As[2][8192];
  __shared__ u16 Bs[2][8192];
  int tid = threadIdx.x;
  int lane = tid & 63, w = tid >> 6;
  int l15 = lane & 15, g = lane >> 4;
  int m0 = blockIdx.x * 128, n0 = blockIdx.y * 128;
  int wr = w >> 1, wc = w & 1;
  int nt = K >> 6;

  f32x4 acc[4][4];
  #pragma unroll
  for (int i = 0; i < 4; ++i)
    #pragma unroll
    for (int j = 0; j < 4; ++j)
      #pragma unroll
      for (int r = 0; r < 4; ++r) acc[i][j][r] = 0.f;

  auto stage = [&](int t, int buf) {
    int k0 = t << 6;
    #pragma unroll
    for (int j = 0; j < 4; ++j) {
      int idx = j * 256 + tid;
      int row = idx >> 3, cs = (idx & 7) ^ (row & 7);
      gload16(A + (size_t)(m0 + row) * K + k0 + cs * 8, &As[buf][idx * 8]);
    }
    #pragma unroll
    for (int j = 0; j < 4; ++j) {
      int idx = j * 256 + tid;
      int row = idx >> 3, cs = (idx & 7) ^ (row & 7);
      gload16(Bt + (size_t)(n0 + row) * K + k0 + cs * 8, &Bs[buf][idx * 8]);
    }
  };

  stage(0, 0);
  for (int t = 0; t < nt; ++t) {
    int cur = t & 1;
    if (t + 1 < nt) {
      stage(t + 1, cur ^ 1);
      WAITVM(8);
    } else {
      WAITVM(0);
    }
    BAR();
    short8v af[4][2], bf[4][2];
    #pragma unroll
    for (int mi = 0; mi < 4; ++mi) {
      int row = wr * 64 + mi * 16 + l15;
      #pragma unroll
      for (int ks = 0; ks < 2; ++ks) {
        int ch = (ks * 4 + g) ^ (row & 7);
        af[mi][ks] = *(const short8v*)&As[cur][row * 64 + ch * 8];
      }
    }
    #pragma unroll
    for (int ni = 0; ni < 4; ++ni) {
      int row = wc * 64 + ni * 16 + l15;
      #pragma unroll
      for (int ks = 0; ks < 2; ++ks) {
        int ch = (ks * 4 + g) ^ (row & 7);
        bf[ni][ks] = *(const short8v*)&Bs[cur][row * 64 + ch * 8];
      }
    }
    #pragma unroll
    for (int mi = 0; mi < 4; ++mi)
      #pragma unroll
      for (int ni = 0; ni < 4; ++ni) {
        acc[mi][ni] = MFMA16(af[mi][0], bf[ni][0], acc[mi][ni]);
        acc[mi][ni] = MFMA16(af[mi][1], bf[ni][1], acc[mi][ni]);
      }
    BAR();
  }

  #pragma unroll
  for (int mi = 0; mi < 4; ++mi) {
    #pragma unroll
    for (int ni = 0; ni < 4; ++ni) {
      int mrow = m0 + wr * 64 + mi * 16 + g * 4;
      int ncol = n0 + wc * 64 + ni * 16 + l15;
      if (MODE == 0) {
        int head = ncol >> 9, dv = ncol & (DM - 1);
        int bb = mrow >> 10, t0 = mrow & (TT - 1);
        ushort4v pk;
        #pragma unroll
        for (int r = 0; r < 4; ++r) pk[r] = bf16_bits(acc[mi][ni][r]);
        *(ushort4v*)((u16*)Oo + ((((size_t)bb * NH + head) * DM + dv) << 10) + t0) = pk;
      } else if (MODE == 1) {
        float bv = bias[ncol];
        #pragma unroll
        for (int r = 0; r < 4; ++r)
          ((u16*)Oo)[(size_t)(mrow + r) * N + ncol] =
              bf16_bits(fmaxf(acc[mi][ni][r] + bv, 0.f));
      } else if (MODE == 2) {
        #pragma unroll
        for (int r = 0; r < 4; ++r)
          ((float*)Oo)[(size_t)(mrow + r) * N + ncol] = acc[mi][ni][r];
      } else {
        float bv = bias[ncol];
        #pragma unroll
        for (int r = 0; r < 4; ++r)
          ((float*)Oo)[(size_t)(mrow + r) * N + ncol] = acc[mi][ni][r] + bv;
      }
    }
  }
}

// ---------------- hi/lo bf16 MFMA GEMM for Q/K (3-term, exact to ~1e-4) ------
// BK=32; LDS row = 128B: chunks 0-3 = hi k, 4-7 = lo k. Output hi/lo bf16
// to [b][h][t][dk]. M=8192, N=512 fixed.
__global__ __launch_bounds__(256, 2) void gemm_qk(
    const u16* __restrict__ Ah, const u16* __restrict__ Al,
    const u16* __restrict__ Bh, const u16* __restrict__ Bl,
    u16* __restrict__ Oh, u16* __restrict__ Ol, int K) {
  __shared__ u16 As[2][8192];
  __shared__ u16 Bs[2][8192];
  int tid = threadIdx.x;
  int lane = tid & 63, w = tid >> 6;
  int l15 = lane & 15, g = lane >> 4;
  int m0 = blockIdx.x * 128, n0 = blockIdx.y * 128;
  int wr = w >> 1, wc = w & 1;
  int nt = K >> 5;

  f32x4 acc[4][4];
  #pragma unroll
  for (int i = 0; i < 4; ++i)
    #pragma unroll
    for (int j = 0; j < 4; ++j)
      #pragma unroll
      for (int r = 0; r < 4; ++r) acc[i][j][r] = 0.f;

  auto stage = [&](int t, int buf) {
    int k0 = t << 5;
    #pragma unroll
    for (int j = 0; j < 4; ++j) {
      int idx = j * 256 + tid;
      int row = idx >> 3, cs = (idx & 7) ^ (row & 7);
      const u16* src = (cs < 4) ? Ah : Al;
      gload16(src + (size_t)(m0 + row) * K + k0 + (cs & 3) * 8, &As[buf][idx * 8]);
    }
    #pragma unroll
    for (int j = 0; j < 4; ++j) {
      int idx = j * 256 + tid;
      int row = idx >> 3, cs = (idx & 7) ^ (row & 7);
      const u16* src = (cs < 4) ? Bh : Bl;
      gload16(src + (size_t)(n0 + row) * K + k0 + (cs & 3) * 8, &Bs[buf][idx * 8]);
    }
  };

  stage(0, 0);
  for (int t = 0; t < nt; ++t) {
    int cur = t & 1;
    if (t + 1 < nt) {
      stage(t + 1, cur ^ 1);
      WAITVM(8);
    } else {
      WAITVM(0);
    }
    BAR();
    short8v ah[4], al[4], bh[4], bl[4];
    #pragma unroll
    for (int mi = 0; mi < 4; ++mi) {
      int row = wr * 64 + mi * 16 + l15;
      ah[mi] = *(const short8v*)&As[cur][row * 64 + (g ^ (row & 7)) * 8];
      al[mi] = *(const short8v*)&As[cur][row * 64 + ((g + 4) ^ (row & 7)) * 8];
    }
    #pragma unroll
    for (int ni = 0; ni < 4; ++ni) {
      int row = wc * 64 + ni * 16 + l15;
      bh[ni] = *(const short8v*)&Bs[cur][row * 64 + (g ^ (row & 7)) * 8];
      bl[ni] = *(const short8v*)&Bs[cur][row * 64 + ((g + 4) ^ (row & 7)) * 8];
    }
    #pragma unroll
    for (int mi = 0; mi < 4; ++mi)
      #pragma unroll
      for (int ni = 0; ni < 4; ++ni) {
        acc[mi][ni] = MFMA16(ah[mi], bh[ni], acc[mi][ni]);
        acc[mi][ni] = MFMA16(al[mi], bh[ni], acc[mi][ni]);
        acc[mi][ni] = MFMA16(ah[mi], bl[ni], acc[mi][ni]);
      }
    BAR();
  }

  #pragma unroll
  for (int mi = 0; mi < 4; ++mi) {
    #pragma unroll
    for (int ni = 0; ni < 4; ++ni) {
      int mrow = m0 + wr * 64 + mi * 16 + g * 4;
      int ncol = n0 + wc * 64 + ni * 16 + l15;
      int head = ncol >> 6, dk = ncol & (DK - 1);
      int bb = mrow >> 10;
      #pragma unroll
      for (int r = 0; r < 4; ++r) {
        int t = (mrow + r) & (TT - 1);
        size_t ad = (((size_t)bb * NH + head) * TT + t) * DK + dk;
        float v = acc[mi][ni][r];
        u16 hb = bf16_bits(v);
        Oh[ad] = hb;
        Ol[ad] = bf16_bits(v - bits_to_f32(hb));
      }
    }
  }
}

// ---------------- MFMA flash attention (unchanged from round 2) ----------------
__global__ __launch_bounds__(256, 2) void attn_mfma_kernel(
    const __hip_bfloat16* __restrict__ qh_, const __hip_bfloat16* __restrict__ ql_,
    const __hip_bfloat16* __restrict__ kh_, const __hip_bfloat16* __restrict__ kl_,
    const __hip_bfloat16* __restrict__ vt_, float* __restrict__ o) {
  __shared__ __align__(16) u16 Pl[64 * 64];
  __shared__ float rs_lds[64];

  const u16* qhp = (const u16*)qh_;
  const u16* qlp = (const u16*)ql_;
  const u16* khp = (const u16*)kh_;
  const u16* klp = (const u16*)kl_;
  const u16* vtp = (const u16*)vt_;

  int tid = threadIdx.x;
  int lane = tid & 63;
  int w = tid >> 6;
  int l15 = lane & 15, g = lane >> 4;
  int blk = blockIdx.x;
  int bh = blk & 63;
  int tt = 15 - (blk >> 6);

  if (tid < 64) rs_lds[tid] = 0.f;

  size_t qbase = (((size_t)bh * TT) + tt * 64 + w * 16 + l15) * DK + g * 8;
  short8v qfh[2], qfl[2];
  qfh[0] = *(const short8v*)(qhp + qbase);
  qfh[1] = *(const short8v*)(qhp + qbase + 32);
  qfl[0] = *(const short8v*)(qlp + qbase);
  qfl[1] = *(const short8v*)(qlp + qbase + 32);

  f32x4 oacc[4][8];
  #pragma unroll
  for (int qt = 0; qt < 4; ++qt)
    #pragma unroll
    for (int dv = 0; dv < 8; ++dv)
      #pragma unroll
      for (int r = 0; r < 4; ++r) oacc[qt][dv][r] = 0.f;

  __syncthreads();

  for (int ot = 0; ot <= tt; ++ot) {
    int ob = ot * 64;
    bool diag = (ot == tt);
    size_t kbase = (((size_t)bh * TT) + ob + l15) * DK + g * 8;
    short8v kfh[4][2], kfl[4][2];
    #pragma unroll
    for (int ct = 0; ct < 4; ++ct) {
      size_t kb2 = kbase + (size_t)ct * 16 * DK;
      kfh[ct][0] = *(const short8v*)(khp + kb2);
      kfh[ct][1] = *(const short8v*)(khp + kb2 + 32);
      kfl[ct][0] = *(const short8v*)(klp + kb2);
      kfl[ct][1] = *(const short8v*)(klp + kb2 + 32);
    }
    f32x4 sacc[4];
    #pragma unroll
    for (int ct = 0; ct < 4; ++ct)
      #pragma unroll
      for (int r = 0; r < 4; ++r) sacc[ct][r] = 0.f;
    #pragma unroll
    for (int ct = 0; ct < 4; ++ct) {
      #pragma unroll
      for (int ks = 0; ks < 2; ++ks) {
        sacc[ct] = MFMA16(qfh[ks], kfh[ct][ks], sacc[ct]);
        sacc[ct] = MFMA16(qfl[ks], kfh[ct][ks], sacc[ct]);
        sacc[ct] = MFMA16(qfh[ks], kfl[ct][ks], sacc[ct]);
      }
    }
    float psum[4] = {0.f, 0.f, 0.f, 0.f};
    #pragma unroll
    for (int ct = 0; ct < 4; ++ct) {
      #pragma unroll
      for (int r = 0; r < 4; ++r) {
        float s = sacc[ct][r];
        float p = __expf(fminf(s, 50.f));
        if (diag && (ct * 16 + l15 > w * 16 + g * 4 + r)) p = 0.f;
        psum[r] += p;
        int q = w * 16 + g * 4 + r;
        int byte = (q * 128 + (ct * 16 + l15) * 2) ^ ((q & 7) << 4);
        *(__hip_bfloat16*)((char*)Pl + byte) = __float2bfloat16(p);
      }
    }
    #pragma unroll
    for (int r = 0; r < 4; ++r) {
      float v = psum[r];
      v += __shfl_xor(v, 1, 16);
      v += __shfl_xor(v, 2, 16);
      v += __shfl_xor(v, 4, 16);
      v += __shfl_xor(v, 8, 16);
      if (l15 == 0) rs_lds[w * 16 + g * 4 + r] += v;
    }
    __syncthreads();
    #pragma unroll
    for (int ks = 0; ks < 2; ++ks) {
      short8v pf[4];
      #pragma unroll
      for (int qt = 0; qt < 4; ++qt) {
        int q = qt * 16 + l15;
        int byte = (q * 128 + ks * 64 + g * 16) ^ ((q & 7) << 4);
        pf[qt] = *(short8v*)((char*)Pl + byte);
      }
      size_t vbase = ((size_t)bh * DM + w * 128 + l15) * TT + ob + ks * 32 + g * 8;
      #pragma unroll
      for (int dv = 0; dv < 8; ++dv) {
        short8v vf = *(const short8v*)(vtp + vbase + (size_t)dv * 16 * TT);
        #pragma unroll
        for (int qt = 0; qt < 4; ++qt)
          oacc[qt][dv] = MFMA16(pf[qt], vf, oacc[qt][dv]);
      }
    }
    __syncthreads();
  }
  int b = bh >> 3, hh = bh & 7;
  #pragma unroll
  for (int qt = 0; qt < 4; ++qt) {
    #pragma unroll
    for (int r = 0; r < 4; ++r) {
      int q = qt * 16 + g * 4 + r;
      float rs = 1.0f / (rs_lds[q] + 1e-10f);
      size_t rowbase = ((size_t)(b * TT + tt * 64 + q)) * (NH * DM) + hh * DM + w * 128 + l15;
      #pragma unroll
      for (int dv = 0; dv < 8; ++dv)
        o[rowbase + dv * 16] = oacc[qt][dv][r] * rs;
    }
  }
}

extern "C" void kernel_launch(void* const* d_in, const int* in_sizes, int n_in,
                              void* d_out, int out_size, void* d_ws, size_t ws_size,
                              hipStream_t stream) {
  (void)in_sizes; (void)n_in; (void)out_size; (void)ws_size;
  const int*   x   = (const int*)d_in[0];
  const float* emb = (const float*)d_in[3];
  const float* pos = (const float*)d_in[4];
  const float* wq  = (const float*)d_in[5];
  const float* wk  = (const float*)d_in[6];
  const float* wv  = (const float*)d_in[7];
  const float* m0  = (const float*)d_in[8];
  const float* mb  = (const float*)d_in[9];
  const float* m1  = (const float*)d_in[10];
  const float* ue  = (const float*)d_in[11];
  const float* ub  = (const float*)d_in[12];
  float* out = (float*)d_out;
  float* ws  = (float*)d_ws;

  const int M = BB * TT;

  // ws layout (56.4 MB): h f32 | hh | hl bf16 | yb f32 | ueT bf16
  float* h   = ws;
  u16*   hh  = (u16*)(ws + 4194304);
  u16*   hl  = hh + 4194304;
  float* yb  = ws + 8388608;
  u16*   ueT = (u16*)(ws + 12582912);

  // d_out layout: vt bf16 [0,67MB) | qk hi/lo [67,99MB) | wT [99,110MB) | Ob f32 [134,268MB)
  u16* outus = (u16*)d_out;
  u16* vt = outus;
  u16* qhb = outus + 33554432;
  u16* qlb = qhb + 4194304;
  u16* khb = qlb + 4194304;
  u16* klb = khb + 4194304;
  u16* wT  = klb + 4194304;
  u16 *wqTh = wT, *wqTl = wT + 262144, *wkTh = wT + 524288, *wkTl = wT + 786432;
  u16* wvT = wT + 1048576;
  u16* w0T = wT + 3145728;
  u16* w1T = wT + 4194304;
  float* Ob = out + 33554432;
  u16* hid = outus;   // MLP hidden reuses vt region (dead after attention)

  embed_ln_kernel<<<M, 256, 0, stream>>>(x, emb, pos, h, hh, hl);

  for (int l = 0; l < NL; ++l) {
    transpose_layer<<<dim3(32, 64, 5), 256, 0, stream>>>(
        wq + (size_t)l * NH * DM * DK, wk + (size_t)l * NH * DM * DK,
        wv + (size_t)l * NH * DM * DM, m0 + (size_t)l * DM * DH,
        m1 + (size_t)l * DH * DM,
        wqTh, wqTl, wkTh, wkTl, wvT, w0T, w1T);
    gemm_qk<<<dim3(64, 4), 256, 0, stream>>>(hh, hl, wqTh, wqTl, qhb, qlb, DM);
    gemm_qk<<<dim3(64, 4), 256, 0, stream>>>(hh, hl, wkTh, wkTl, khb, klb, DM);
    gemm_mfma<0><<<dim3(64, 32), 256, 0, stream>>>(hh, wvT, nullptr, vt, M, NH * DM, DM);
    attn_mfma_kernel<<<BB * NH * (TT / 64), 256, 0, stream>>>(
        (const __hip_bfloat16*)qhb, (const __hip_bfloat16*)qlb,
        (const __hip_bfloat16*)khb, (const __hip_bfloat16*)klb,
        (const __hip_bfloat16*)vt, Ob);
    ln_residual_kernel<<<M, 256, 0, stream>>>(h, Ob, NH * DM, NH, hh, hl);
    gemm_mfma<1><<<dim3(64, 16), 256, 0, stream>>>(hh, w0T, mb + (size_t)l * DH, hid, M, DH, DM);
    gemm_mfma<2><<<dim3(64, 4), 256, 0, stream>>>(hid, w1T, nullptr, yb, M, DM, DH);
    ln_residual_kernel<<<M, 256, 0, stream>>>(h, yb, DM, 1, hh, hl);
  }
  transpose_ue<<<dim3(8, 128), 256, 0, stream>>>(ue, ueT);
  gemm_mfma<3><<<dim3(64, 64), 256, 0, stream>>>(hh, ueT, ub, out, M, ND, DM);
}

// Round 4
// 2586.934 us; speedup vs baseline: 12.8477x; 1.2863x over previous
//
#include <hip/hip_runtime.h>
#include <hip/hip_bf16.h>

#define BB 8
#define TT 1024
#define DM 512
#define NH 8
#define DK 64
#define DH 2048
#define NL 8
#define ND 8192

typedef __attribute__((ext_vector_type(8))) short short8v;
typedef __attribute__((ext_vector_type(8))) _Float16 f16x8;
typedef __attribute__((ext_vector_type(4))) float f32x4;
typedef __attribute__((ext_vector_type(4))) unsigned short ushort4v;
typedef unsigned short u16;

#define MFMA16(a, b, c) __builtin_amdgcn_mfma_f32_16x16x32_bf16(a, b, c, 0, 0, 0)
#define MFMAH(a, b, c)  __builtin_amdgcn_mfma_f32_16x16x32_f16(a, b, c, 0, 0, 0)

__device__ __forceinline__ u16 bf16_bits(float f) {
  union { __hip_bfloat16 h; u16 u; } cv;
  cv.h = __float2bfloat16(f);
  return cv.u;
}
__device__ __forceinline__ float bits_to_f32(u16 u) {
  union { __hip_bfloat16 h; u16 u; } cv;
  cv.u = u;
  return __bfloat162float(cv.h);
}

__device__ __forceinline__ void gload16(const void* g, void* l) {
  __builtin_amdgcn_global_load_lds(
      (const __attribute__((address_space(1))) unsigned int*)g,
      (__attribute__((address_space(3))) unsigned int*)l, 16, 0, 0);
}

#define WAITVM(N) asm volatile("s_waitcnt vmcnt(" #N ")" ::: "memory")
#define BAR() { __builtin_amdgcn_s_barrier(); asm volatile("" ::: "memory"); }

// ---------------- block reduce (256 threads, 2 accumulators) ----------------
__device__ __forceinline__ void block_reduce2(float& a, float& b) {
  #pragma unroll
  for (int off = 32; off > 0; off >>= 1) {
    a += __shfl_down(a, off, 64);
    b += __shfl_down(b, off, 64);
  }
  __shared__ float sa[4], sb[4];
  int w = threadIdx.x >> 6;
  if ((threadIdx.x & 63) == 0) { sa[w] = a; sb[w] = b; }
  __syncthreads();
  if (threadIdx.x == 0) {
    sa[0] = sa[0] + sa[1] + sa[2] + sa[3];
    sb[0] = sb[0] + sb[1] + sb[2] + sb[3];
  }
  __syncthreads();
  a = sa[0]; b = sb[0];
}

__device__ __forceinline__ void store_hilo(u16* hh, u16* hl, size_t i, float v) {
  u16 hb = bf16_bits(v);
  hh[i] = hb;
  hl[i] = bf16_bits(v - bits_to_f32(hb));
}

// ---------------- embedding + LN ----------------
__global__ __launch_bounds__(256) void embed_ln_kernel(
    const int* __restrict__ x, const float* __restrict__ emb,
    const float* __restrict__ pos, float* __restrict__ h,
    u16* __restrict__ hh, u16* __restrict__ hl) {
  int bt = blockIdx.x;
  int t = bt & (TT - 1);
  int tid = threadIdx.x;
  int row = x[bt];
  float v0 = emb[(size_t)row * DM + tid]       + pos[(size_t)t * DM + tid];
  float v1 = emb[(size_t)row * DM + tid + 256] + pos[(size_t)t * DM + tid + 256];
  float s = v0 + v1, sq = v0 * v0 + v1 * v1;
  block_reduce2(s, sq);
  float mu  = s * (1.0f / DM);
  float var = sq * (1.0f / DM) - mu * mu;
  float rs  = rsqrtf(var + 1e-5f);
  float r0 = (v0 - mu) * rs, r1 = (v1 - mu) * rs;
  h[(size_t)bt * DM + tid] = r0;
  h[(size_t)bt * DM + tid + 256] = r1;
  store_hilo(hh, hl, (size_t)bt * DM + tid, r0);
  store_hilo(hh, hl, (size_t)bt * DM + tid + 256, r1);
}

// ---------------- h = LN(h + sum_i add[...]) ----------------
template<bool BF16ADD>
__global__ __launch_bounds__(256) void ln_residual_kernel(
    float* __restrict__ h, const void* __restrict__ add_, int rowStride, int nsum,
    u16* __restrict__ hh, u16* __restrict__ hl) {
  int bt = blockIdx.x;
  int tid = threadIdx.x;
  size_t base = (size_t)bt * (size_t)rowStride;
  float v0 = h[(size_t)bt * DM + tid];
  float v1 = h[(size_t)bt * DM + tid + 256];
  if (BF16ADD) {
    const u16* add = (const u16*)add_;
    for (int i = 0; i < nsum; ++i) {
      v0 += bits_to_f32(add[base + (size_t)i * DM + tid]);
      v1 += bits_to_f32(add[base + (size_t)i * DM + tid + 256]);
    }
  } else {
    const float* add = (const float*)add_;
    for (int i = 0; i < nsum; ++i) {
      v0 += add[base + (size_t)i * DM + tid];
      v1 += add[base + (size_t)i * DM + tid + 256];
    }
  }
  float s = v0 + v1, sq = v0 * v0 + v1 * v1;
  block_reduce2(s, sq);
  float mu  = s * (1.0f / DM);
  float var = sq * (1.0f / DM) - mu * mu;
  float rs  = rsqrtf(var + 1e-5f);
  float r0 = (v0 - mu) * rs, r1 = (v1 - mu) * rs;
  h[(size_t)bt * DM + tid] = r0;
  h[(size_t)bt * DM + tid + 256] = r1;
  store_hilo(hh, hl, (size_t)bt * DM + tid, r0);
  store_hilo(hh, hl, (size_t)bt * DM + tid + 256, r1);
}

// ---------------- weight transpose + bf16 convert ----------------
__device__ __forceinline__ void tconv_body(
    const float* __restrict__ in, u16* __restrict__ oh, u16* __restrict__ ol,
    int K, int Nb, bool hilo, float (*T)[65]) {
  int tid = threadIdx.x;
  int k0 = blockIdx.x * 64, n0 = blockIdx.y * 64;
  int g = n0 / Nb;
  const float* src = in + (size_t)g * K * Nb + (n0 - g * Nb);
  #pragma unroll
  for (int rep = 0; rep < 16; ++rep) {
    int idx = rep * 256 + tid;
    int i = idx >> 6, j = idx & 63;
    T[i][j] = src[(size_t)(k0 + i) * Nb + j];
  }
  __syncthreads();
  #pragma unroll
  for (int rep = 0; rep < 16; ++rep) {
    int idx = rep * 256 + tid;
    int j = idx >> 6, i = idx & 63;
    float v = T[i][j];
    size_t oa = (size_t)(n0 + j) * K + k0 + i;
    u16 hb = bf16_bits(v);
    oh[oa] = hb;
    if (hilo) ol[oa] = bf16_bits(v - bits_to_f32(hb));
  }
}

__global__ __launch_bounds__(256) void transpose_layer(
    const float* __restrict__ wq, const float* __restrict__ wk,
    const float* __restrict__ wv, const float* __restrict__ w0,
    const float* __restrict__ w1,
    u16* qh, u16* ql, u16* kh, u16* kl, u16* vT, u16* t0, u16* t1) {
  __shared__ float T[64][65];
  int z = blockIdx.z;
  const float* in;
  u16 *oh, *ol = nullptr;
  int K, Nb, gx, gy;
  bool hilo = false;
  switch (z) {
    case 0: in = wq; oh = qh; ol = ql; K = 512;  Nb = 64;   gx = 8;  gy = 8;  hilo = true; break;
    case 1: in = wk; oh = kh; ol = kl; K = 512;  Nb = 64;   gx = 8;  gy = 8;  hilo = true; break;
    case 2: in = wv; oh = vT;          K = 512;  Nb = 512;  gx = 8;  gy = 64; break;
    case 3: in = w0; oh = t0;          K = 512;  Nb = 2048; gx = 8;  gy = 32; break;
    default: in = w1; oh = t1;         K = 2048; Nb = 512;  gx = 32; gy = 8;  break;
  }
  if ((int)blockIdx.x >= gx || (int)blockIdx.y >= gy) return;
  tconv_body(in, oh, ol, K, Nb, hilo, T);
}

__global__ __launch_bounds__(256) void transpose_ue(
    const float* __restrict__ ue, u16* __restrict__ ueT) {
  __shared__ float T[64][65];
  tconv_body(ue, ueT, nullptr, 512, 8192, false, T);
}

// ---------------- bf16 MFMA GEMM: C[M][N] = A[M][K] @ Bt[N][K]^T ----------------
// MODE 0: Vt bf16 out [b][h][dv][t]   MODE 1: bf16 bias+relu row-major
// MODE 2: f32 row-major               MODE 3: f32 + bias row-major
template<int MODE>
__global__ __launch_bounds__(256, 2) void gemm_mfma(
    const u16* __restrict__ A, const u16* __restrict__ Bt,
    const float* __restrict__ bias, void* __restrict__ Oo,
    int M, int N, int K) {
  __shared__ u16 As[2][8192];
  __shared__ u16 Bs[2][8192];
  int tid = threadIdx.x;
  int lane = tid & 63, w = tid >> 6;
  int l15 = lane & 15, g = lane >> 4;
  int m0 = blockIdx.x * 128, n0 = blockIdx.y * 128;
  int wr = w >> 1, wc = w & 1;
  int nt = K >> 6;

  f32x4 acc[4][4];
  #pragma unroll
  for (int i = 0; i < 4; ++i)
    #pragma unroll
    for (int j = 0; j < 4; ++j)
      #pragma unroll
      for (int r = 0; r < 4; ++r) acc[i][j][r] = 0.f;

  auto stage = [&](int t, int buf) {
    int k0 = t << 6;
    #pragma unroll
    for (int j = 0; j < 4; ++j) {
      int idx = j * 256 + tid;
      int row = idx >> 3, cs = (idx & 7) ^ (row & 7);
      gload16(A + (size_t)(m0 + row) * K + k0 + cs * 8, &As[buf][idx * 8]);
    }
    #pragma unroll
    for (int j = 0; j < 4; ++j) {
      int idx = j * 256 + tid;
      int row = idx >> 3, cs = (idx & 7) ^ (row & 7);
      gload16(Bt + (size_t)(n0 + row) * K + k0 + cs * 8, &Bs[buf][idx * 8]);
    }
  };

  stage(0, 0);
  for (int t = 0; t < nt; ++t) {
    int cur = t & 1;
    if (t + 1 < nt) {
      stage(t + 1, cur ^ 1);
      WAITVM(8);
    } else {
      WAITVM(0);
    }
    BAR();
    short8v af[4][2], bf[4][2];
    #pragma unroll
    for (int mi = 0; mi < 4; ++mi) {
      int row = wr * 64 + mi * 16 + l15;
      #pragma unroll
      for (int ks = 0; ks < 2; ++ks) {
        int ch = (ks * 4 + g) ^ (row & 7);
        af[mi][ks] = *(const short8v*)&As[cur][row * 64 + ch * 8];
      }
    }
    #pragma unroll
    for (int ni = 0; ni < 4; ++ni) {
      int row = wc * 64 + ni * 16 + l15;
      #pragma unroll
      for (int ks = 0; ks < 2; ++ks) {
        int ch = (ks * 4 + g) ^ (row & 7);
        bf[ni][ks] = *(const short8v*)&Bs[cur][row * 64 + ch * 8];
      }
    }
    #pragma unroll
    for (int mi = 0; mi < 4; ++mi)
      #pragma unroll
      for (int ni = 0; ni < 4; ++ni) {
        acc[mi][ni] = MFMA16(af[mi][0], bf[ni][0], acc[mi][ni]);
        acc[mi][ni] = MFMA16(af[mi][1], bf[ni][1], acc[mi][ni]);
      }
    BAR();
  }

  #pragma unroll
  for (int mi = 0; mi < 4; ++mi) {
    #pragma unroll
    for (int ni = 0; ni < 4; ++ni) {
      int mrow = m0 + wr * 64 + mi * 16 + g * 4;
      int ncol = n0 + wc * 64 + ni * 16 + l15;
      if (MODE == 0) {
        int head = ncol >> 9, dv = ncol & (DM - 1);
        int bb = mrow >> 10, t0 = mrow & (TT - 1);
        ushort4v pk;
        #pragma unroll
        for (int r = 0; r < 4; ++r) pk[r] = bf16_bits(acc[mi][ni][r]);
        *(ushort4v*)((u16*)Oo + ((((size_t)bb * NH + head) * DM + dv) << 10) + t0) = pk;
      } else if (MODE == 1) {
        float bv = bias[ncol];
        #pragma unroll
        for (int r = 0; r < 4; ++r)
          ((u16*)Oo)[(size_t)(mrow + r) * N + ncol] =
              bf16_bits(fmaxf(acc[mi][ni][r] + bv, 0.f));
      } else if (MODE == 2) {
        #pragma unroll
        for (int r = 0; r < 4; ++r)
          ((float*)Oo)[(size_t)(mrow + r) * N + ncol] = acc[mi][ni][r];
      } else {
        float bv = bias[ncol];
        #pragma unroll
        for (int r = 0; r < 4; ++r)
          ((float*)Oo)[(size_t)(mrow + r) * N + ncol] = acc[mi][ni][r] + bv;
      }
    }
  }
}

// ---------------- hi/lo bf16 MFMA GEMM for Q/K -> f16 output ----------------
// A,B carry hi/lo bf16 (3-term exact); output single f16 [b][h][t][dk].
__global__ __launch_bounds__(256, 2) void gemm_qk(
    const u16* __restrict__ Ah, const u16* __restrict__ Al,
    const u16* __restrict__ Bh, const u16* __restrict__ Bl,
    _Float16* __restrict__ Oq, int K) {
  __shared__ u16 As[2][8192];
  __shared__ u16 Bs[2][8192];
  int tid = threadIdx.x;
  int lane = tid & 63, w = tid >> 6;
  int l15 = lane & 15, g = lane >> 4;
  int m0 = blockIdx.x * 128, n0 = blockIdx.y * 128;
  int wr = w >> 1, wc = w & 1;
  int nt = K >> 5;

  f32x4 acc[4][4];
  #pragma unroll
  for (int i = 0; i < 4; ++i)
    #pragma unroll
    for (int j = 0; j < 4; ++j)
      #pragma unroll
      for (int r = 0; r < 4; ++r) acc[i][j][r] = 0.f;

  auto stage = [&](int t, int buf) {
    int k0 = t << 5;
    #pragma unroll
    for (int j = 0; j < 4; ++j) {
      int idx = j * 256 + tid;
      int row = idx >> 3, cs = (idx & 7) ^ (row & 7);
      const u16* src = (cs < 4) ? Ah : Al;
      gload16(src + (size_t)(m0 + row) * K + k0 + (cs & 3) * 8, &As[buf][idx * 8]);
    }
    #pragma unroll
    for (int j = 0; j < 4; ++j) {
      int idx = j * 256 + tid;
      int row = idx >> 3, cs = (idx & 7) ^ (row & 7);
      const u16* src = (cs < 4) ? Bh : Bl;
      gload16(src + (size_t)(n0 + row) * K + k0 + (cs & 3) * 8, &Bs[buf][idx * 8]);
    }
  };

  stage(0, 0);
  for (int t = 0; t < nt; ++t) {
    int cur = t & 1;
    if (t + 1 < nt) {
      stage(t + 1, cur ^ 1);
      WAITVM(8);
    } else {
      WAITVM(0);
    }
    BAR();
    short8v ah[4], al[4], bh[4], bl[4];
    #pragma unroll
    for (int mi = 0; mi < 4; ++mi) {
      int row = wr * 64 + mi * 16 + l15;
      ah[mi] = *(const short8v*)&As[cur][row * 64 + (g ^ (row & 7)) * 8];
      al[mi] = *(const short8v*)&As[cur][row * 64 + ((g + 4) ^ (row & 7)) * 8];
    }
    #pragma unroll
    for (int ni = 0; ni < 4; ++ni) {
      int row = wc * 64 + ni * 16 + l15;
      bh[ni] = *(const short8v*)&Bs[cur][row * 64 + (g ^ (row & 7)) * 8];
      bl[ni] = *(const short8v*)&Bs[cur][row * 64 + ((g + 4) ^ (row & 7)) * 8];
    }
    #pragma unroll
    for (int mi = 0; mi < 4; ++mi)
      #pragma unroll
      for (int ni = 0; ni < 4; ++ni) {
        acc[mi][ni] = MFMA16(ah[mi], bh[ni], acc[mi][ni]);
        acc[mi][ni] = MFMA16(al[mi], bh[ni], acc[mi][ni]);
        acc[mi][ni] = MFMA16(ah[mi], bl[ni], acc[mi][ni]);
      }
    BAR();
  }

  #pragma unroll
  for (int mi = 0; mi < 4; ++mi) {
    #pragma unroll
    for (int ni = 0; ni < 4; ++ni) {
      int mrow = m0 + wr * 64 + mi * 16 + g * 4;
      int ncol = n0 + wc * 64 + ni * 16 + l15;
      int head = ncol >> 6, dk = ncol & (DK - 1);
      int bb = mrow >> 10;
      #pragma unroll
      for (int r = 0; r < 4; ++r) {
        int t = (mrow + r) & (TT - 1);
        size_t ad = (((size_t)bb * NH + head) * TT + t) * DK + dk;
        Oq[ad] = (_Float16)acc[mi][ni][r];
      }
    }
  }
}

// ---------------- MFMA flash attention v2 (f16 S, pipelined, bf16 O) --------
// Per block: (b,h, 64-row q-tile). 4 waves. Wave w: S rows [w*16,w*16+16),
// PV dv-cols [w*128,(w+1)*128). P double-buffered in LDS -> 1 barrier/tile.
// V ks=0 loads hoisted above the barrier to hide global latency.
__global__ __launch_bounds__(256, 2) void attn_mfma_kernel(
    const _Float16* __restrict__ qp, const _Float16* __restrict__ kp,
    const __hip_bfloat16* __restrict__ vt_, u16* __restrict__ o) {
  __shared__ __align__(16) u16 Pl[2][64 * 64];
  __shared__ float rs_lds[64];

  const u16* vtp = (const u16*)vt_;

  int tid = threadIdx.x;
  int lane = tid & 63;
  int w = tid >> 6;
  int l15 = lane & 15, g = lane >> 4;
  int blk = blockIdx.x;
  int bh = blk & 63;
  int tt = 15 - (blk >> 6);          // heaviest causal tiles dispatch first

  if (tid < 64) rs_lds[tid] = 0.f;

  size_t qbase = (((size_t)bh * TT) + tt * 64 + w * 16 + l15) * DK + g * 8;
  f16x8 qf[2];
  qf[0] = *(const f16x8*)(qp + qbase);
  qf[1] = *(const f16x8*)(qp + qbase + 32);

  f32x4 oacc[4][8];
  #pragma unroll
  for (int qt = 0; qt < 4; ++qt)
    #pragma unroll
    for (int dv = 0; dv < 8; ++dv)
      #pragma unroll
      for (int r = 0; r < 4; ++r) oacc[qt][dv][r] = 0.f;

  __syncthreads();

  for (int ot = 0; ot <= tt; ++ot) {
    int ob = ot * 64;
    bool diag = (ot == tt);
    int buf = ot & 1;
    // K fragments (f16): col=l15 -> o_local = ct*16+l15
    size_t kbase = (((size_t)bh * TT) + ob + l15) * DK + g * 8;
    f16x8 kf[4][2];
    #pragma unroll
    for (int ct = 0; ct < 4; ++ct) {
      kf[ct][0] = *(const f16x8*)(kp + kbase + (size_t)ct * 16 * DK);
      kf[ct][1] = *(const f16x8*)(kp + kbase + (size_t)ct * 16 * DK + 32);
    }
    f32x4 sacc[4];
    #pragma unroll
    for (int ct = 0; ct < 4; ++ct)
      #pragma unroll
      for (int r = 0; r < 4; ++r) sacc[ct][r] = 0.f;
    #pragma unroll
    for (int ct = 0; ct < 4; ++ct)
      #pragma unroll
      for (int ks = 0; ks < 2; ++ks)
        sacc[ct] = MFMAH(qf[ks], kf[ct][ks], sacc[ct]);
    // hoist V ks=0 loads (independent of P) above the barrier
    size_t vbase = ((size_t)bh * DM + w * 128 + l15) * TT + ob + g * 8;
    short8v vf0[8];
    #pragma unroll
    for (int dv = 0; dv < 8; ++dv)
      vf0[dv] = *(const short8v*)(vtp + vbase + (size_t)dv * 16 * TT);
    // exp + mask + row-sum + P->LDS (bf16, XOR-swizzled)
    float psum[4] = {0.f, 0.f, 0.f, 0.f};
    #pragma unroll
    for (int ct = 0; ct < 4; ++ct) {
      #pragma unroll
      for (int r = 0; r < 4; ++r) {
        float s = sacc[ct][r];
        float p = __expf(fminf(s, 50.f));
        if (diag && (ct * 16 + l15 > w * 16 + g * 4 + r)) p = 0.f;
        psum[r] += p;
        int q = w * 16 + g * 4 + r;
        int byte = (q * 128 + (ct * 16 + l15) * 2) ^ ((q & 7) << 4);
        *(u16*)((char*)Pl[buf] + byte) = bf16_bits(p);
      }
    }
    #pragma unroll
    for (int r = 0; r < 4; ++r) {
      float v = psum[r];
      v += __shfl_xor(v, 1, 16);
      v += __shfl_xor(v, 2, 16);
      v += __shfl_xor(v, 4, 16);
      v += __shfl_xor(v, 8, 16);
      if (l15 == 0) rs_lds[w * 16 + g * 4 + r] += v;
    }
    __syncthreads();
    // PV: issue ks=1 V loads first, then compute ks=0 with vf0
    short8v vf1[8];
    #pragma unroll
    for (int dv = 0; dv < 8; ++dv)
      vf1[dv] = *(const short8v*)(vtp + vbase + 32 + (size_t)dv * 16 * TT);
    short8v pf[4];
    #pragma unroll
    for (int qt = 0; qt < 4; ++qt) {
      int q = qt * 16 + l15;
      int byte = (q * 128 + g * 16) ^ ((q & 7) << 4);
      pf[qt] = *(short8v*)((char*)Pl[buf] + byte);
    }
    #pragma unroll
    for (int dv = 0; dv < 8; ++dv)
      #pragma unroll
      for (int qt = 0; qt < 4; ++qt)
        oacc[qt][dv] = MFMA16(pf[qt], vf0[dv], oacc[qt][dv]);
    #pragma unroll
    for (int qt = 0; qt < 4; ++qt) {
      int q = qt * 16 + l15;
      int byte = (q * 128 + 64 + g * 16) ^ ((q & 7) << 4);
      pf[qt] = *(short8v*)((char*)Pl[buf] + byte);
    }
    #pragma unroll
    for (int dv = 0; dv < 8; ++dv)
      #pragma unroll
      for (int qt = 0; qt < 4; ++qt)
        oacc[qt][dv] = MFMA16(pf[qt], vf1[dv], oacc[qt][dv]);
  }
  // epilogue: normalize, write O bf16 [bt][h*512+dv]
  __syncthreads();
  int b = bh >> 3, hh2 = bh & 7;
  #pragma unroll
  for (int qt = 0; qt < 4; ++qt) {
    #pragma unroll
    for (int r = 0; r < 4; ++r) {
      int q = qt * 16 + g * 4 + r;
      float rs = 1.0f / (rs_lds[q] + 1e-10f);
      size_t rowbase = ((size_t)(b * TT + tt * 64 + q)) * (NH * DM) + hh2 * DM + w * 128 + l15;
      #pragma unroll
      for (int dv = 0; dv < 8; ++dv)
        o[rowbase + dv * 16] = bf16_bits(oacc[qt][dv][r] * rs);
    }
  }
}

extern "C" void kernel_launch(void* const* d_in, const int* in_sizes, int n_in,
                              void* d_out, int out_size, void* d_ws, size_t ws_size,
                              hipStream_t stream) {
  (void)in_sizes; (void)n_in; (void)out_size; (void)ws_size;
  const int*   x   = (const int*)d_in[0];
  const float* emb = (const float*)d_in[3];
  const float* pos = (const float*)d_in[4];
  const float* wq  = (const float*)d_in[5];
  const float* wk  = (const float*)d_in[6];
  const float* wv  = (const float*)d_in[7];
  const float* m0  = (const float*)d_in[8];
  const float* mb  = (const float*)d_in[9];
  const float* m1  = (const float*)d_in[10];
  const float* ue  = (const float*)d_in[11];
  const float* ub  = (const float*)d_in[12];
  float* out = (float*)d_out;
  float* ws  = (float*)d_ws;

  const int M = BB * TT;

  // ws layout: h f32 | hh | hl bf16 | yb f32 | ueT bf16
  float* h   = ws;
  u16*   hh  = (u16*)(ws + 4194304);
  u16*   hl  = hh + 4194304;
  float* yb  = ws + 8388608;
  u16*   ueT = (u16*)(ws + 12582912);

  // d_out scratch layout (u16 units):
  // vt [0,33.5M) | q f16 [33.5M,37.7M) | k f16 [37.7M,41.9M) | wT [41.9M,47.2M)
  // | Ob bf16 [67.1M,100.7M)
  u16* outus = (u16*)d_out;
  u16* vt  = outus;
  _Float16* qf16 = (_Float16*)(outus + 33554432);
  _Float16* kf16 = (_Float16*)(outus + 37748736);
  u16* wT  = outus + 41943040;
  u16 *wqTh = wT, *wqTl = wT + 262144, *wkTh = wT + 524288, *wkTl = wT + 786432;
  u16* wvT = wT + 1048576;
  u16* w0T = wT + 3145728;
  u16* w1T = wT + 4194304;
  u16* Ob  = outus + 67108864;       // bf16 [bt][h*512+dv]
  u16* hid = outus;                  // MLP hidden reuses vt region (dead)

  embed_ln_kernel<<<M, 256, 0, stream>>>(x, emb, pos, h, hh, hl);

  for (int l = 0; l < NL; ++l) {
    transpose_layer<<<dim3(32, 64, 5), 256, 0, stream>>>(
        wq + (size_t)l * NH * DM * DK, wk + (size_t)l * NH * DM * DK,
        wv + (size_t)l * NH * DM * DM, m0 + (size_t)l * DM * DH,
        m1 + (size_t)l * DH * DM,
        wqTh, wqTl, wkTh, wkTl, wvT, w0T, w1T);
    gemm_qk<<<dim3(64, 4), 256, 0, stream>>>(hh, hl, wqTh, wqTl, qf16, DM);
    gemm_qk<<<dim3(64, 4), 256, 0, stream>>>(hh, hl, wkTh, wkTl, kf16, DM);
    gemm_mfma<0><<<dim3(64, 32), 256, 0, stream>>>(hh, wvT, nullptr, vt, M, NH * DM, DM);
    attn_mfma_kernel<<<BB * NH * (TT / 64), 256, 0, stream>>>(
        qf16, kf16, (const __hip_bfloat16*)vt, Ob);
    ln_residual_kernel<true><<<M, 256, 0, stream>>>(h, Ob, NH * DM, NH, hh, hl);
    gemm_mfma<1><<<dim3(64, 16), 256, 0, stream>>>(hh, w0T, mb + (size_t)l * DH, hid, M, DH, DM);
    gemm_mfma<2><<<dim3(64, 4), 256, 0, stream>>>(hid, w1T, nullptr, yb, M, DM, DH);
    ln_residual_kernel<false><<<M, 256, 0, stream>>>(h, yb, DM, 1, hh, hl);
  }
  transpose_ue<<<dim3(8, 128), 256, 0, stream>>>(ue, ueT);
  gemm_mfma<3><<<dim3(64, 64), 256, 0, stream>>>(hh, ueT, ub, out, M, ND, DM);
}

// Round 5
// 2350.557 us; speedup vs baseline: 14.1397x; 1.1006x over previous
//
#include <hip/hip_runtime.h>
#include <hip/hip_bf16.h>

#define BB 8
#define TT 1024
#define DM 512
#define NH 8
#define DK 64
#define DH 2048
#define NL 8
#define ND 8192

typedef __attribute__((ext_vector_type(8))) short short8v;
typedef __attribute__((ext_vector_type(8))) _Float16 f16x8;
typedef __attribute__((ext_vector_type(4))) float f32x4;
typedef __attribute__((ext_vector_type(4))) unsigned short ushort4v;
typedef unsigned short u16;

#define MFMA16(a, b, c) __builtin_amdgcn_mfma_f32_16x16x32_bf16(a, b, c, 0, 0, 0)
#define MFMAH(a, b, c)  __builtin_amdgcn_mfma_f32_16x16x32_f16(a, b, c, 0, 0, 0)

__device__ __forceinline__ u16 bf16_bits(float f) {
  union { __hip_bfloat16 h; u16 u; } cv;
  cv.h = __float2bfloat16(f);
  return cv.u;
}
__device__ __forceinline__ float bits_to_f32(u16 u) {
  union { __hip_bfloat16 h; u16 u; } cv;
  cv.u = u;
  return __bfloat162float(cv.h);
}

__device__ __forceinline__ void gload16(const void* g, void* l) {
  __builtin_amdgcn_global_load_lds(
      (const __attribute__((address_space(1))) unsigned int*)g,
      (__attribute__((address_space(3))) unsigned int*)l, 16, 0, 0);
}

#define WAITVM(N) asm volatile("s_waitcnt vmcnt(" #N ")" ::: "memory")
#define BAR() { __builtin_amdgcn_s_barrier(); asm volatile("" ::: "memory"); }

// ---------------- block reduce (256 threads, 2 accumulators) ----------------
__device__ __forceinline__ void block_reduce2(float& a, float& b) {
  #pragma unroll
  for (int off = 32; off > 0; off >>= 1) {
    a += __shfl_down(a, off, 64);
    b += __shfl_down(b, off, 64);
  }
  __shared__ float sa[4], sb[4];
  int w = threadIdx.x >> 6;
  if ((threadIdx.x & 63) == 0) { sa[w] = a; sb[w] = b; }
  __syncthreads();
  if (threadIdx.x == 0) {
    sa[0] = sa[0] + sa[1] + sa[2] + sa[3];
    sb[0] = sb[0] + sb[1] + sb[2] + sb[3];
  }
  __syncthreads();
  a = sa[0]; b = sb[0];
}

// ---------------- embedding + LN ----------------
__global__ __launch_bounds__(256) void embed_ln_kernel(
    const int* __restrict__ x, const float* __restrict__ emb,
    const float* __restrict__ pos, float* __restrict__ h,
    u16* __restrict__ hh, _Float16* __restrict__ hf) {
  int bt = blockIdx.x;
  int t = bt & (TT - 1);
  int tid = threadIdx.x;
  int row = x[bt];
  float v0 = emb[(size_t)row * DM + tid]       + pos[(size_t)t * DM + tid];
  float v1 = emb[(size_t)row * DM + tid + 256] + pos[(size_t)t * DM + tid + 256];
  float s = v0 + v1, sq = v0 * v0 + v1 * v1;
  block_reduce2(s, sq);
  float mu  = s * (1.0f / DM);
  float var = sq * (1.0f / DM) - mu * mu;
  float rs  = rsqrtf(var + 1e-5f);
  float r0 = (v0 - mu) * rs, r1 = (v1 - mu) * rs;
  h[(size_t)bt * DM + tid] = r0;
  h[(size_t)bt * DM + tid + 256] = r1;
  hh[(size_t)bt * DM + tid] = bf16_bits(r0);
  hh[(size_t)bt * DM + tid + 256] = bf16_bits(r1);
  hf[(size_t)bt * DM + tid] = (_Float16)r0;
  hf[(size_t)bt * DM + tid + 256] = (_Float16)r1;
}

// ---------------- h = LN(h + sum_i add[...]) ----------------
template<bool BF16ADD>
__global__ __launch_bounds__(256) void ln_residual_kernel(
    float* __restrict__ h, const void* __restrict__ add_, int rowStride, int nsum,
    u16* __restrict__ hh, _Float16* __restrict__ hf) {
  int bt = blockIdx.x;
  int tid = threadIdx.x;
  size_t base = (size_t)bt * (size_t)rowStride;
  float v0 = h[(size_t)bt * DM + tid];
  float v1 = h[(size_t)bt * DM + tid + 256];
  if (BF16ADD) {
    const u16* add = (const u16*)add_;
    for (int i = 0; i < nsum; ++i) {
      v0 += bits_to_f32(add[base + (size_t)i * DM + tid]);
      v1 += bits_to_f32(add[base + (size_t)i * DM + tid + 256]);
    }
  } else {
    const float* add = (const float*)add_;
    for (int i = 0; i < nsum; ++i) {
      v0 += add[base + (size_t)i * DM + tid];
      v1 += add[base + (size_t)i * DM + tid + 256];
    }
  }
  float s = v0 + v1, sq = v0 * v0 + v1 * v1;
  block_reduce2(s, sq);
  float mu  = s * (1.0f / DM);
  float var = sq * (1.0f / DM) - mu * mu;
  float rs  = rsqrtf(var + 1e-5f);
  float r0 = (v0 - mu) * rs, r1 = (v1 - mu) * rs;
  h[(size_t)bt * DM + tid] = r0;
  h[(size_t)bt * DM + tid + 256] = r1;
  hh[(size_t)bt * DM + tid] = bf16_bits(r0);
  hh[(size_t)bt * DM + tid + 256] = bf16_bits(r1);
  hf[(size_t)bt * DM + tid] = (_Float16)r0;
  hf[(size_t)bt * DM + tid + 256] = (_Float16)r1;
}

// ---------------- weight transpose + convert (compact 1D grid) ----------------
// slices: [0,64) wq->f16, [64,128) wk->f16, [128,640) wv->bf16,
//         [640,896) w0->bf16, [896,1152) w1->bf16
__global__ __launch_bounds__(256) void transpose_layer(
    const float* __restrict__ wq, const float* __restrict__ wk,
    const float* __restrict__ wv, const float* __restrict__ w0,
    const float* __restrict__ w1,
    _Float16* __restrict__ qT, _Float16* __restrict__ kT,
    u16* __restrict__ vT, u16* __restrict__ t0, u16* __restrict__ t1) {
  __shared__ float T[64][65];
  int t = blockIdx.x;
  const float* in;
  _Float16* of = nullptr;
  u16* ob = nullptr;
  int K, Nb;
  if (t < 64)       { in = wq; of = qT; K = 512;  Nb = 64; }
  else if (t < 128) { in = wk; of = kT; K = 512;  Nb = 64;   t -= 64; }
  else if (t < 640) { in = wv; ob = vT; K = 512;  Nb = 512;  t -= 128; }
  else if (t < 896) { in = w0; ob = t0; K = 512;  Nb = 2048; t -= 640; }
  else              { in = w1; ob = t1; K = 2048; Nb = 512;  t -= 896; }
  int ntx = K >> 6;
  int k0 = (t % ntx) * 64, n0 = (t / ntx) * 64;
  int g = n0 / Nb;
  const float* src = in + (size_t)g * K * Nb + (n0 - g * Nb);
  int tid = threadIdx.x;
  #pragma unroll
  for (int rep = 0; rep < 16; ++rep) {
    int idx = rep * 256 + tid;
    int i = idx >> 6, j = idx & 63;
    T[i][j] = src[(size_t)(k0 + i) * Nb + j];
  }
  __syncthreads();
  #pragma unroll
  for (int rep = 0; rep < 16; ++rep) {
    int idx = rep * 256 + tid;
    int j = idx >> 6, i = idx & 63;
    float v = T[i][j];
    size_t oa = (size_t)(n0 + j) * K + k0 + i;
    if (of) of[oa] = (_Float16)v;
    else    ob[oa] = bf16_bits(v);
  }
}

__global__ __launch_bounds__(256) void transpose_ue(
    const float* __restrict__ ue, u16* __restrict__ ueT) {
  __shared__ float T[64][65];
  int tid = threadIdx.x;
  int k0 = blockIdx.x * 64, n0 = blockIdx.y * 64;
  #pragma unroll
  for (int rep = 0; rep < 16; ++rep) {
    int idx = rep * 256 + tid;
    int i = idx >> 6, j = idx & 63;
    T[i][j] = ue[(size_t)(k0 + i) * ND + n0 + j];
  }
  __syncthreads();
  #pragma unroll
  for (int rep = 0; rep < 16; ++rep) {
    int idx = rep * 256 + tid;
    int j = idx >> 6, i = idx & 63;
    ueT[(size_t)(n0 + j) * DM + k0 + i] = bf16_bits(T[i][j]);
  }
}

// ---------------- bf16 MFMA GEMM: C[M][N] = A[M][K] @ Bt[N][K]^T ----------------
// MODE 0: Vt bf16 out [b][h][dv][t]   MODE 1: bf16 bias+relu row-major
// MODE 2: f32 row-major               MODE 3: f32 + bias row-major
template<int MODE>
__global__ __launch_bounds__(256, 2) void gemm_mfma(
    const u16* __restrict__ A, const u16* __restrict__ Bt,
    const float* __restrict__ bias, void* __restrict__ Oo,
    int M, int N, int K) {
  __shared__ u16 As[2][8192];
  __shared__ u16 Bs[2][8192];
  int tid = threadIdx.x;
  int lane = tid & 63, w = tid >> 6;
  int l15 = lane & 15, g = lane >> 4;
  int m0 = blockIdx.x * 128, n0 = blockIdx.y * 128;
  int wr = w >> 1, wc = w & 1;
  int nt = K >> 6;

  f32x4 acc[4][4];
  #pragma unroll
  for (int i = 0; i < 4; ++i)
    #pragma unroll
    for (int j = 0; j < 4; ++j)
      #pragma unroll
      for (int r = 0; r < 4; ++r) acc[i][j][r] = 0.f;

  auto stage = [&](int t, int buf) {
    int k0 = t << 6;
    #pragma unroll
    for (int j = 0; j < 4; ++j) {
      int idx = j * 256 + tid;
      int row = idx >> 3, cs = (idx & 7) ^ (row & 7);
      gload16(A + (size_t)(m0 + row) * K + k0 + cs * 8, &As[buf][idx * 8]);
    }
    #pragma unroll
    for (int j = 0; j < 4; ++j) {
      int idx = j * 256 + tid;
      int row = idx >> 3, cs = (idx & 7) ^ (row & 7);
      gload16(Bt + (size_t)(n0 + row) * K + k0 + cs * 8, &Bs[buf][idx * 8]);
    }
  };

  stage(0, 0);
  for (int t = 0; t < nt; ++t) {
    int cur = t & 1;
    if (t + 1 < nt) {
      stage(t + 1, cur ^ 1);
      WAITVM(8);
    } else {
      WAITVM(0);
    }
    BAR();
    short8v af[4][2], bf[4][2];
    #pragma unroll
    for (int mi = 0; mi < 4; ++mi) {
      int row = wr * 64 + mi * 16 + l15;
      #pragma unroll
      for (int ks = 0; ks < 2; ++ks) {
        int ch = (ks * 4 + g) ^ (row & 7);
        af[mi][ks] = *(const short8v*)&As[cur][row * 64 + ch * 8];
      }
    }
    #pragma unroll
    for (int ni = 0; ni < 4; ++ni) {
      int row = wc * 64 + ni * 16 + l15;
      #pragma unroll
      for (int ks = 0; ks < 2; ++ks) {
        int ch = (ks * 4 + g) ^ (row & 7);
        bf[ni][ks] = *(const short8v*)&Bs[cur][row * 64 + ch * 8];
      }
    }
    __builtin_amdgcn_s_setprio(1);
    #pragma unroll
    for (int mi = 0; mi < 4; ++mi)
      #pragma unroll
      for (int ni = 0; ni < 4; ++ni) {
        acc[mi][ni] = MFMA16(af[mi][0], bf[ni][0], acc[mi][ni]);
        acc[mi][ni] = MFMA16(af[mi][1], bf[ni][1], acc[mi][ni]);
      }
    __builtin_amdgcn_s_setprio(0);
    BAR();
  }

  #pragma unroll
  for (int mi = 0; mi < 4; ++mi) {
    #pragma unroll
    for (int ni = 0; ni < 4; ++ni) {
      int mrow = m0 + wr * 64 + mi * 16 + g * 4;
      int ncol = n0 + wc * 64 + ni * 16 + l15;
      if (MODE == 0) {
        int head = ncol >> 9, dv = ncol & (DM - 1);
        int bb = mrow >> 10, t0 = mrow & (TT - 1);
        ushort4v pk;
        #pragma unroll
        for (int r = 0; r < 4; ++r) pk[r] = bf16_bits(acc[mi][ni][r]);
        *(ushort4v*)((u16*)Oo + ((((size_t)bb * NH + head) * DM + dv) << 10) + t0) = pk;
      } else if (MODE == 1) {
        float bv = bias[ncol];
        #pragma unroll
        for (int r = 0; r < 4; ++r)
          ((u16*)Oo)[(size_t)(mrow + r) * N + ncol] =
              bf16_bits(fmaxf(acc[mi][ni][r] + bv, 0.f));
      } else if (MODE == 2) {
        #pragma unroll
        for (int r = 0; r < 4; ++r)
          ((float*)Oo)[(size_t)(mrow + r) * N + ncol] = acc[mi][ni][r];
      } else {
        float bv = bias[ncol];
        #pragma unroll
        for (int r = 0; r < 4; ++r)
          ((float*)Oo)[(size_t)(mrow + r) * N + ncol] = acc[mi][ni][r] + bv;
      }
    }
  }
}

// ---------------- f16 MFMA GEMM for Q/K -> f16 output [b][h][t][dk] ----------
__global__ __launch_bounds__(256, 2) void gemm_qk_f16(
    const _Float16* __restrict__ A, const _Float16* __restrict__ Bt,
    _Float16* __restrict__ Oq, int K) {
  __shared__ _Float16 As[2][8192];
  __shared__ _Float16 Bs[2][8192];
  int tid = threadIdx.x;
  int lane = tid & 63, w = tid >> 6;
  int l15 = lane & 15, g = lane >> 4;
  int m0 = blockIdx.x * 128, n0 = blockIdx.y * 128;
  int wr = w >> 1, wc = w & 1;
  int nt = K >> 6;

  f32x4 acc[4][4];
  #pragma unroll
  for (int i = 0; i < 4; ++i)
    #pragma unroll
    for (int j = 0; j < 4; ++j)
      #pragma unroll
      for (int r = 0; r < 4; ++r) acc[i][j][r] = 0.f;

  auto stage = [&](int t, int buf) {
    int k0 = t << 6;
    #pragma unroll
    for (int j = 0; j < 4; ++j) {
      int idx = j * 256 + tid;
      int row = idx >> 3, cs = (idx & 7) ^ (row & 7);
      gload16(A + (size_t)(m0 + row) * K + k0 + cs * 8, &As[buf][idx * 8]);
    }
    #pragma unroll
    for (int j = 0; j < 4; ++j) {
      int idx = j * 256 + tid;
      int row = idx >> 3, cs = (idx & 7) ^ (row & 7);
      gload16(Bt + (size_t)(n0 + row) * K + k0 + cs * 8, &Bs[buf][idx * 8]);
    }
  };

  stage(0, 0);
  for (int t = 0; t < nt; ++t) {
    int cur = t & 1;
    if (t + 1 < nt) {
      stage(t + 1, cur ^ 1);
      WAITVM(8);
    } else {
      WAITVM(0);
    }
    BAR();
    f16x8 af[4][2], bf[4][2];
    #pragma unroll
    for (int mi = 0; mi < 4; ++mi) {
      int row = wr * 64 + mi * 16 + l15;
      #pragma unroll
      for (int ks = 0; ks < 2; ++ks) {
        int ch = (ks * 4 + g) ^ (row & 7);
        af[mi][ks] = *(const f16x8*)&As[cur][row * 64 + ch * 8];
      }
    }
    #pragma unroll
    for (int ni = 0; ni < 4; ++ni) {
      int row = wc * 64 + ni * 16 + l15;
      #pragma unroll
      for (int ks = 0; ks < 2; ++ks) {
        int ch = (ks * 4 + g) ^ (row & 7);
        bf[ni][ks] = *(const f16x8*)&Bs[cur][row * 64 + ch * 8];
      }
    }
    __builtin_amdgcn_s_setprio(1);
    #pragma unroll
    for (int mi = 0; mi < 4; ++mi)
      #pragma unroll
      for (int ni = 0; ni < 4; ++ni) {
        acc[mi][ni] = MFMAH(af[mi][0], bf[ni][0], acc[mi][ni]);
        acc[mi][ni] = MFMAH(af[mi][1], bf[ni][1], acc[mi][ni]);
      }
    __builtin_amdgcn_s_setprio(0);
    BAR();
  }

  #pragma unroll
  for (int mi = 0; mi < 4; ++mi) {
    #pragma unroll
    for (int ni = 0; ni < 4; ++ni) {
      int mrow = m0 + wr * 64 + mi * 16 + g * 4;
      int ncol = n0 + wc * 64 + ni * 16 + l15;
      int head = ncol >> 6, dk = ncol & (DK - 1);
      int bb = mrow >> 10;
      #pragma unroll
      for (int r = 0; r < 4; ++r) {
        int t = (mrow + r) & (TT - 1);
        Oq[(((size_t)bb * NH + head) * TT + t) * DK + dk] = (_Float16)acc[mi][ni][r];
      }
    }
  }
}

// ---------------- MFMA flash attention v3 ----------------
// K staged in LDS (double-buffered, prefetched 1 tile ahead via global_load_lds),
// f16 S, P double-buffered in LDS (1 barrier/tile), bf16 O.
__global__ __launch_bounds__(256, 2) void attn_mfma_kernel(
    const _Float16* __restrict__ qp, const _Float16* __restrict__ kp,
    const __hip_bfloat16* __restrict__ vt_, u16* __restrict__ o) {
  __shared__ __align__(16) u16 Pl[2][64 * 64];
  __shared__ __align__(16) _Float16 Kl[2][64 * 64];
  __shared__ float rs_lds[64];

  const u16* vtp = (const u16*)vt_;
  int tid = threadIdx.x;
  int lane = tid & 63;
  int w = tid >> 6;
  int l15 = lane & 15, g = lane >> 4;
  int blk = blockIdx.x;
  int bh = blk & 63;
  int tt = 15 - (blk >> 6);          // heaviest causal tiles dispatch first

  if (tid < 64) rs_lds[tid] = 0.f;

  auto stageK = [&](int ot, int buf) {
    int ob = ot * 64;
    #pragma unroll
    for (int j = 0; j < 2; ++j) {
      int idx = j * 256 + tid;                 // 16B chunk id, 0..511
      int row = idx >> 3, cs = (idx & 7) ^ (row & 7);
      gload16(kp + ((size_t)bh * TT + ob + row) * DK + cs * 8, &Kl[buf][idx * 8]);
    }
  };

  size_t qbase = (((size_t)bh * TT) + tt * 64 + w * 16 + l15) * DK + g * 8;
  f16x8 qf[2];
  qf[0] = *(const f16x8*)(qp + qbase);
  qf[1] = *(const f16x8*)(qp + qbase + 32);

  f32x4 oacc[4][8];
  #pragma unroll
  for (int qt = 0; qt < 4; ++qt)
    #pragma unroll
    for (int dv = 0; dv < 8; ++dv)
      #pragma unroll
      for (int r = 0; r < 4; ++r) oacc[qt][dv][r] = 0.f;

  stageK(0, 0);
  WAITVM(0);
  __syncthreads();

  for (int ot = 0; ot <= tt; ++ot) {
    int ob = ot * 64;
    bool diag = (ot == tt);
    int buf = ot & 1;
    // prefetch next K tile (drained by this tile's vmcnt(0)+barrier)
    if (ot < tt) stageK(ot + 1, buf ^ 1);
    // S = Q K^T from LDS K (swizzled ds_read_b128)
    f32x4 sacc[4];
    #pragma unroll
    for (int ct = 0; ct < 4; ++ct)
      #pragma unroll
      for (int r = 0; r < 4; ++r) sacc[ct][r] = 0.f;
    __builtin_amdgcn_s_setprio(1);
    #pragma unroll
    for (int ct = 0; ct < 4; ++ct) {
      int row = ct * 16 + l15;
      f16x8 k0 = *(const f16x8*)&Kl[buf][row * 64 + ((g) ^ (row & 7)) * 8];
      f16x8 k1 = *(const f16x8*)&Kl[buf][row * 64 + ((4 + g) ^ (row & 7)) * 8];
      sacc[ct] = MFMAH(qf[0], k0, sacc[ct]);
      sacc[ct] = MFMAH(qf[1], k1, sacc[ct]);
    }
    __builtin_amdgcn_s_setprio(0);
    // V ks=0 loads (independent of P) issued before exp
    size_t vbase = ((size_t)bh * DM + w * 128 + l15) * TT + ob + g * 8;
    short8v vf0[8];
    #pragma unroll
    for (int dv = 0; dv < 8; ++dv)
      vf0[dv] = *(const short8v*)(vtp + vbase + (size_t)dv * 16 * TT);
    // exp + mask + row-sum + P->LDS (bf16, XOR-swizzled)
    float psum[4] = {0.f, 0.f, 0.f, 0.f};
    #pragma unroll
    for (int ct = 0; ct < 4; ++ct) {
      #pragma unroll
      for (int r = 0; r < 4; ++r) {
        float s = sacc[ct][r];
        float p = __expf(fminf(s, 50.f));
        if (diag && (ct * 16 + l15 > w * 16 + g * 4 + r)) p = 0.f;
        psum[r] += p;
        int q = w * 16 + g * 4 + r;
        int byte = (q * 128 + (ct * 16 + l15) * 2) ^ ((q & 7) << 4);
        *(u16*)((char*)Pl[buf] + byte) = bf16_bits(p);
      }
    }
    #pragma unroll
    for (int r = 0; r < 4; ++r) {
      float v = psum[r];
      v += __shfl_xor(v, 1, 16);
      v += __shfl_xor(v, 2, 16);
      v += __shfl_xor(v, 4, 16);
      v += __shfl_xor(v, 8, 16);
      if (l15 == 0) rs_lds[w * 16 + g * 4 + r] += v;
    }
    WAITVM(0);     // drain K(ot+1) stage + vf0
    BAR();
    // PV: issue ks=1 V loads first, then compute ks=0 with vf0
    short8v vf1[8];
    #pragma unroll
    for (int dv = 0; dv < 8; ++dv)
      vf1[dv] = *(const short8v*)(vtp + vbase + 32 + (size_t)dv * 16 * TT);
    short8v pf[4];
    #pragma unroll
    for (int qt = 0; qt < 4; ++qt) {
      int q = qt * 16 + l15;
      int byte = (q * 128 + g * 16) ^ ((q & 7) << 4);
      pf[qt] = *(short8v*)((char*)Pl[buf] + byte);
    }
    __builtin_amdgcn_s_setprio(1);
    #pragma unroll
    for (int dv = 0; dv < 8; ++dv)
      #pragma unroll
      for (int qt = 0; qt < 4; ++qt)
        oacc[qt][dv] = MFMA16(pf[qt], vf0[dv], oacc[qt][dv]);
    __builtin_amdgcn_s_setprio(0);
    #pragma unroll
    for (int qt = 0; qt < 4; ++qt) {
      int q = qt * 16 + l15;
      int byte = (q * 128 + 64 + g * 16) ^ ((q & 7) << 4);
      pf[qt] = *(short8v*)((char*)Pl[buf] + byte);
    }
    __builtin_amdgcn_s_setprio(1);
    #pragma unroll
    for (int dv = 0; dv < 8; ++dv)
      #pragma unroll
      for (int qt = 0; qt < 4; ++qt)
        oacc[qt][dv] = MFMA16(pf[qt], vf1[dv], oacc[qt][dv]);
    __builtin_amdgcn_s_setprio(0);
  }
  // epilogue: normalize, write O bf16 [bt][h*512+dv]
  __syncthreads();
  int b = bh >> 3, hh2 = bh & 7;
  #pragma unroll
  for (int qt = 0; qt < 4; ++qt) {
    #pragma unroll
    for (int r = 0; r < 4; ++r) {
      int q = qt * 16 + g * 4 + r;
      float rs = 1.0f / (rs_lds[q] + 1e-10f);
      size_t rowbase = ((size_t)(b * TT + tt * 64 + q)) * (NH * DM) + hh2 * DM + w * 128 + l15;
      #pragma unroll
      for (int dv = 0; dv < 8; ++dv)
        o[rowbase + dv * 16] = bf16_bits(oacc[qt][dv][r] * rs);
    }
  }
}

extern "C" void kernel_launch(void* const* d_in, const int* in_sizes, int n_in,
                              void* d_out, int out_size, void* d_ws, size_t ws_size,
                              hipStream_t stream) {
  (void)in_sizes; (void)n_in; (void)out_size; (void)ws_size;
  const int*   x   = (const int*)d_in[0];
  const float* emb = (const float*)d_in[3];
  const float* pos = (const float*)d_in[4];
  const float* wq  = (const float*)d_in[5];
  const float* wk  = (const float*)d_in[6];
  const float* wv  = (const float*)d_in[7];
  const float* m0  = (const float*)d_in[8];
  const float* mb  = (const float*)d_in[9];
  const float* m1  = (const float*)d_in[10];
  const float* ue  = (const float*)d_in[11];
  const float* ub  = (const float*)d_in[12];
  float* out = (float*)d_out;
  float* ws  = (float*)d_ws;

  const int M = BB * TT;

  // ws layout: h f32 | hh bf16 | hf16 f16 | yb f32 | ueT bf16
  float*    h    = ws;
  u16*      hh   = (u16*)(ws + 4194304);
  _Float16* hf16 = (_Float16*)(ws + 6291456);
  float*    yb   = ws + 8388608;
  u16*      ueT  = (u16*)(ws + 12582912);

  // d_out scratch layout (u16 units):
  // vt [0,33.5M) | q f16 [33.5M,+4.2M) | k f16 [37.7M,+4.2M) | wT [41.9M,...)
  // | Ob bf16 [67.1M,+33.5M)
  u16* outus = (u16*)d_out;
  u16* vt = outus;
  _Float16* qf16 = (_Float16*)(outus + 33554432);
  _Float16* kf16 = (_Float16*)(outus + 37748736);
  u16* wT = outus + 41943040;
  _Float16* wqT = (_Float16*)wT;                 //  262144 elems
  _Float16* wkT = (_Float16*)(wT + 262144);      //  262144
  u16* wvT = wT + 524288;                        // 2097152
  u16* w0T = wT + 2621440;                       // 1048576
  u16* w1T = wT + 3670016;                       // 1048576
  u16* Ob  = outus + 67108864;                   // bf16 [bt][h*512+dv]
  u16* hid = outus;                              // MLP hidden reuses vt region

  embed_ln_kernel<<<M, 256, 0, stream>>>(x, emb, pos, h, hh, hf16);

  for (int l = 0; l < NL; ++l) {
    transpose_layer<<<1152, 256, 0, stream>>>(
        wq + (size_t)l * NH * DM * DK, wk + (size_t)l * NH * DM * DK,
        wv + (size_t)l * NH * DM * DM, m0 + (size_t)l * DM * DH,
        m1 + (size_t)l * DH * DM,
        wqT, wkT, wvT, w0T, w1T);
    gemm_qk_f16<<<dim3(64, 4), 256, 0, stream>>>(hf16, wqT, qf16, DM);
    gemm_qk_f16<<<dim3(64, 4), 256, 0, stream>>>(hf16, wkT, kf16, DM);
    gemm_mfma<0><<<dim3(64, 32), 256, 0, stream>>>(hh, wvT, nullptr, vt, M, NH * DM, DM);
    attn_mfma_kernel<<<BB * NH * (TT / 64), 256, 0, stream>>>(
        qf16, kf16, (const __hip_bfloat16*)vt, Ob);
    ln_residual_kernel<true><<<M, 256, 0, stream>>>(h, Ob, NH * DM, NH, hh, hf16);
    gemm_mfma<1><<<dim3(64, 16), 256, 0, stream>>>(hh, w0T, mb + (size_t)l * DH, hid, M, DH, DM);
    gemm_mfma<2><<<dim3(64, 4), 256, 0, stream>>>(hid, w1T, nullptr, yb, M, DM, DH);
    ln_residual_kernel<false><<<M, 256, 0, stream>>>(h, yb, DM, 1, hh, hf16);
  }
  transpose_ue<<<dim3(8, 128), 256, 0, stream>>>(ue, ueT);
  gemm_mfma<3><<<dim3(64, 64), 256, 0, stream>>>(hh, ueT, ub, out, M, ND, DM);
}